// Round 6
// baseline (487.555 us; speedup 1.0000x reference)
//
#include <hip/hip_runtime.h>
#include <math.h>

// GCNGuard forward: 2 layers of {cosine-sim edge attention -> linear -> SPMM}.
// R3: multi-block scan (113us -> ~us).
// R4: att_kernel was latency-bound (65us, 3.26 TB/s, VALUBusy 33%, 4 edges/wave,
//     2 dependent miss latencies per wave). Now 4 edges per 16-lane subgroup:
//     16 independent dwordx4 gathers in flight per wave (4x MLP), uint4 idx loads,
//     epilogue on lanes 0-3 via static-index selects.

constexpr int D_IN = 128;
constexpr int D_H  = 128;
constexpr int D_O  = 64;

typedef unsigned int uint;

// ---------------- node norms: one wave per node (D=128, 2 floats/lane) -------
__global__ __launch_bounds__(256) void node_norm_kernel(
    const float* __restrict__ x, float* __restrict__ nrm, int n) {
  int gid = blockIdx.x * blockDim.x + threadIdx.x;
  int i = gid >> 6;
  if (i >= n) return;
  int l = threadIdx.x & 63;
  float2 v = *reinterpret_cast<const float2*>(x + (size_t)i * 128 + l * 2);
  float s = v.x * v.x + v.y * v.y;
#pragma unroll
  for (int m = 1; m < 64; m <<= 1) s += __shfl_xor(s, m);
  if (l == 0) nrm[i] = sqrtf(s);
}

// ---------------- CSR build --------------------------------------------------
__global__ __launch_bounds__(256) void hist_kernel(
    const int* __restrict__ row, uint* __restrict__ counts, int nE) {
  int e = blockIdx.x * blockDim.x + threadIdx.x;
  if (e < nE) atomicAdd(&counts[row[e]], 1u);
}

// phase 1: per-block exclusive scan of 256 counts, emit block sum
__global__ __launch_bounds__(256) void block_scan_kernel(
    const uint* __restrict__ counts, uint* __restrict__ row_excl,
    uint* __restrict__ blk_sums, int n) {
  __shared__ uint sh[256];
  int t = threadIdx.x;
  int i = blockIdx.x * 256 + t;
  uint v = (i < n) ? counts[i] : 0u;
  sh[t] = v;
  __syncthreads();
#pragma unroll
  for (int off = 1; off < 256; off <<= 1) {
    uint u = (t >= off) ? sh[t - off] : 0u;
    __syncthreads();
    sh[t] += u;
    __syncthreads();
  }
  if (i < n) row_excl[i] = sh[t] - v;         // exclusive-in-block
  if (t == 255) blk_sums[blockIdx.x] = sh[255];
}

// phase 2: scan the block sums (nb <= 256) in one small block
__global__ __launch_bounds__(256) void scan_sums_kernel(
    const uint* __restrict__ blk_sums, uint* __restrict__ blk_offs, int nb) {
  __shared__ uint sh[256];
  int t = threadIdx.x;
  uint v = (t < nb) ? blk_sums[t] : 0u;
  sh[t] = v;
  __syncthreads();
#pragma unroll
  for (int off = 1; off < 256; off <<= 1) {
    uint u = (t >= off) ? sh[t - off] : 0u;
    __syncthreads();
    sh[t] += u;
    __syncthreads();
  }
  if (t < nb) blk_offs[t] = sh[t] - v;        // exclusive block offset
}

// phase 3: add block offsets, materialize row_ptr + cursor, cap row_ptr[n]
__global__ __launch_bounds__(256) void add_offs_kernel(
    uint* __restrict__ row_ptr, uint* __restrict__ cursor,
    const uint* __restrict__ blk_offs, int n, uint nE) {
  int i = blockIdx.x * 256 + threadIdx.x;
  if (i < n) {
    uint v = row_ptr[i] + blk_offs[blockIdx.x];
    row_ptr[i] = v;
    cursor[i] = v;
  }
  if (i == n) row_ptr[n] = nE;                // grid over-covers by <256
}

__global__ __launch_bounds__(256) void scatter_kernel(
    const int* __restrict__ row, const int* __restrict__ col,
    uint* __restrict__ cursor, uint* __restrict__ row_s,
    uint* __restrict__ col_s, int nE) {
  int e = blockIdx.x * blockDim.x + threadIdx.x;
  if (e >= nE) return;
  int r = row[e];
  uint p = atomicAdd(&cursor[r], 1u);
  row_s[p] = (uint)r;
  col_s[p] = (uint)col[e];
}

// ---------------- W transpose (once per call, tiny) --------------------------
__global__ __launch_bounds__(256) void transpose_kernel(
    const float* __restrict__ W, float* __restrict__ Wt, int J, int K) {
  int idx = blockIdx.x * blockDim.x + threadIdx.x;
  if (idx >= J * K) return;
  int j = idx >> 7;        // K == 128 always here
  int k = idx & 127;
  Wt[k * J + j] = W[idx];
}

// ---------------- attention SDDMM: 4 edges per 16-lane subgroup --------------
// 256 thr = 16 subgroups; block covers 64 edges. All 16 x-row gathers issued
// independently -> 4x memory-level parallelism vs 1-edge-per-subgroup.
template <bool MASKED>
__global__ __launch_bounds__(256) void att_kernel(
    const float* __restrict__ x, const float* __restrict__ nrm,
    const uint* __restrict__ row_s, const uint* __restrict__ col_s,
    const float* __restrict__ mask_sim, float* __restrict__ sim_out, int nE) {
  int sg = threadIdx.x >> 4;
  int sl = threadIdx.x & 15;
  int p0 = (blockIdx.x * 16 + sg) * 4;
  if (p0 >= nE) return;

  uint r[4], c[4];
  if (p0 + 3 < nE) {                       // vector idx load (16B-aligned)
    uint4 rr = *reinterpret_cast<const uint4*>(row_s + p0);
    uint4 cc = *reinterpret_cast<const uint4*>(col_s + p0);
    r[0] = rr.x; r[1] = rr.y; r[2] = rr.z; r[3] = rr.w;
    c[0] = cc.x; c[1] = cc.y; c[2] = cc.z; c[3] = cc.w;
  } else {
#pragma unroll
    for (int e = 0; e < 4; ++e) {
      int pe = (p0 + e < nE) ? p0 + e : p0;
      r[e] = row_s[pe]; c[e] = col_s[pe];
    }
  }

  float4 A0[4], A1[4], B0[4], B1[4];
#pragma unroll
  for (int e = 0; e < 4; ++e) {            // 16 independent dwordx4 loads
    const float4* xr = reinterpret_cast<const float4*>(x + (size_t)r[e] * 128);
    const float4* xc = reinterpret_cast<const float4*>(x + (size_t)c[e] * 128);
    A0[e] = xr[sl * 2]; A1[e] = xr[sl * 2 + 1];
    B0[e] = xc[sl * 2]; B1[e] = xc[sl * 2 + 1];
  }

  float d[4];
#pragma unroll
  for (int e = 0; e < 4; ++e) {
    d[e] = A0[e].x * B0[e].x + A0[e].y * B0[e].y + A0[e].z * B0[e].z + A0[e].w * B0[e].w +
           A1[e].x * B1[e].x + A1[e].y * B1[e].y + A1[e].z * B1[e].z + A1[e].w * B1[e].w;
  }
#pragma unroll
  for (int m = 1; m <= 8; m <<= 1) {
#pragma unroll
    for (int e = 0; e < 4; ++e) d[e] += __shfl_xor(d[e], m);
  }

  // epilogue on lanes 0..3, one edge each (static-index selects, no scratch)
  float dv = d[0]; uint rv = r[0], cv = c[0];
  if (sl == 1) { dv = d[1]; rv = r[1]; cv = c[1]; }
  if (sl == 2) { dv = d[2]; rv = r[2]; cv = c[2]; }
  if (sl == 3) { dv = d[3]; rv = r[3]; cv = c[3]; }
  if (sl < 4 && p0 + sl < nE) {
    float sim = dv / fmaxf(nrm[rv] * nrm[cv], 1e-12f);
    bool ok = (sim >= 0.1f);
    if (MASKED) ok = ok && (mask_sim[p0 + sl] > 0.0f);
    sim_out[p0 + sl] = ok ? sim : 0.0f;
  }
}

// ---------------- per-row sums + self-loop weight ---------------------------
__global__ __launch_bounds__(256) void rowdeg_kernel(
    const float* __restrict__ sim_s, const uint* __restrict__ row_ptr,
    float* __restrict__ rowsum, float* __restrict__ wself, int n) {
  int i = blockIdx.x * blockDim.x + threadIdx.x;
  if (i >= n) return;
  uint p0 = row_ptr[i], p1 = row_ptr[i + 1];
  float s = 0.f, d = 0.f;
  for (uint p = p0; p < p1; ++p) {
    float v = sim_s[p];
    s += v;
    if (v > 0.f) d += 1.f;
  }
  rowsum[i] = s;
  wself[i] = expf(1.0f / (d + 1.0f));
}

// ---------------- f32 GEMM: H[M][DOUT] = X[M][128] @ Wt[128][DOUT] + b ------
// 64x64 tile, 4x4 register blocking, conflict-free LDS read paths.
template <int DOUT>
__global__ __launch_bounds__(256) void gemm_kernel(
    const float* __restrict__ X, const float* __restrict__ Wt,
    const float* __restrict__ bias, float* __restrict__ H, int M) {
  __shared__ float xs[64][132];   // +4 pad: a-reads land 2-way (free)
  __shared__ float wl[128][64];   // [k][j], staged linearly -> conflict-free
  int i0 = blockIdx.x * 64;
  int j0 = blockIdx.y * 64;
  int t = threadIdx.x;
#pragma unroll
  for (int it = 0; it < 8; ++it) {           // stage W block: 2048 float4
    int idx = it * 256 + t;
    int k = idx >> 4, jq = idx & 15;
    float4 v = *reinterpret_cast<const float4*>(Wt + (size_t)k * DOUT + j0 + jq * 4);
    *reinterpret_cast<float4*>(&wl[k][jq * 4]) = v;
  }
#pragma unroll
  for (int it = 0; it < 8; ++it) {           // stage X tile: 64 rows x 128
    int i = it * 8 + (t >> 5);
    int kq = t & 31;
    int row = i0 + i;
    float4 v = make_float4(0.f, 0.f, 0.f, 0.f);
    if (row < M) v = *reinterpret_cast<const float4*>(X + (size_t)row * 128 + kq * 4);
    *reinterpret_cast<float4*>(&xs[i][kq * 4]) = v;
  }
  __syncthreads();
  int cg = t & 15, rg = t >> 4;
  int r0 = rg * 4, c0 = cg * 4;
  float acc[4][4] = {};
#pragma unroll 8
  for (int k = 0; k < 128; ++k) {
    float4 b4 = *reinterpret_cast<const float4*>(&wl[k][c0]);
    float a0 = xs[r0 + 0][k], a1 = xs[r0 + 1][k];
    float a2 = xs[r0 + 2][k], a3 = xs[r0 + 3][k];
    acc[0][0] += a0 * b4.x; acc[0][1] += a0 * b4.y; acc[0][2] += a0 * b4.z; acc[0][3] += a0 * b4.w;
    acc[1][0] += a1 * b4.x; acc[1][1] += a1 * b4.y; acc[1][2] += a1 * b4.z; acc[1][3] += a1 * b4.w;
    acc[2][0] += a2 * b4.x; acc[2][1] += a2 * b4.y; acc[2][2] += a2 * b4.z; acc[2][3] += a2 * b4.w;
    acc[3][0] += a3 * b4.x; acc[3][1] += a3 * b4.y; acc[3][2] += a3 * b4.z; acc[3][3] += a3 * b4.w;
  }
  float4 bb = *reinterpret_cast<const float4*>(bias + j0 + c0);
#pragma unroll
  for (int r = 0; r < 4; ++r) {
    int row = i0 + r0 + r;
    if (row < M) {
      float4 o = make_float4(acc[r][0] + bb.x, acc[r][1] + bb.y,
                             acc[r][2] + bb.z, acc[r][3] + bb.w);
      *reinterpret_cast<float4*>(H + (size_t)row * DOUT + j0 + c0) = o;
    }
  }
}

// ---------------- SPMM: wave per row, register accum, fused epilogue --------
template <int D, bool RELU, bool WRITE_NORM>
__global__ __launch_bounds__(256) void spmm_kernel(
    const float* __restrict__ H, const float* __restrict__ sim_s,
    const uint* __restrict__ col_s, const uint* __restrict__ row_ptr,
    const float* __restrict__ rowsum, const float* __restrict__ wself,
    float* __restrict__ out, float* __restrict__ norm_out, int n) {
  int gid = blockIdx.x * blockDim.x + threadIdx.x;
  int i = gid >> 6;
  if (i >= n) return;
  int l = threadIdx.x & 63;
  float ws = wself[i];
  float inv = 1.0f / fmaxf(rowsum[i], 1e-30f);
  uint p1 = row_ptr[i + 1];

  if constexpr (D == 128) {
    float2 hv = *reinterpret_cast<const float2*>(H + (size_t)i * 128 + l * 2);
    float ax = ws * hv.x, ay = ws * hv.y;
    for (uint p = row_ptr[i]; p < p1; ++p) {
      float s = sim_s[p];
      if (s > 0.0f) {                       // wave-uniform branch
        float w = expf(s * inv);
        uint c = col_s[p];
        float2 hc = *reinterpret_cast<const float2*>(H + (size_t)c * 128 + l * 2);
        ax += w * hc.x;
        ay += w * hc.y;
      }
    }
    if (RELU) { ax = fmaxf(ax, 0.f); ay = fmaxf(ay, 0.f); }
    float2 o; o.x = ax; o.y = ay;
    *reinterpret_cast<float2*>(out + (size_t)i * 128 + l * 2) = o;
    if (WRITE_NORM) {
      float s = ax * ax + ay * ay;
#pragma unroll
      for (int m = 1; m < 64; m <<= 1) s += __shfl_xor(s, m);
      if (l == 0) norm_out[i] = sqrtf(s);
    }
  } else {  // D == 64
    float a = ws * H[(size_t)i * 64 + l];
    for (uint p = row_ptr[i]; p < p1; ++p) {
      float s = sim_s[p];
      if (s > 0.0f) {
        float w = expf(s * inv);
        uint c = col_s[p];
        a += w * H[(size_t)c * 64 + l];
      }
    }
    if (RELU) a = fmaxf(a, 0.f);
    out[(size_t)i * 64 + l] = a;
    if (WRITE_NORM) {
      float s = a * a;
#pragma unroll
      for (int m = 1; m < 64; m <<= 1) s += __shfl_xor(s, m);
      if (l == 0) norm_out[i] = sqrtf(s);
    }
  }
}

// ---------------- launch -----------------------------------------------------
extern "C" void kernel_launch(void* const* d_in, const int* in_sizes, int n_in,
                              void* d_out, int out_size, void* d_ws, size_t ws_size,
                              hipStream_t stream) {
  const float* x  = (const float*)d_in[0];
  const float* W0 = (const float*)d_in[1];
  const float* b0 = (const float*)d_in[2];
  const float* W1 = (const float*)d_in[3];
  const float* b1 = (const float*)d_in[4];
  const int* erow = (const int*)d_in[5];
  const int* ecol = (const int*)d_in[6];
  float* out = (float*)d_out;

  int nN = in_sizes[0] / D_IN;  // 50000
  int nE = in_sizes[5];         // 800000
  int nBlk = (nN + 255) / 256;  // 196 scan blocks

  char* w = (char*)d_ws;
  auto alloc = [&](size_t bytes) {
    char* p = w;
    w += (bytes + 255) & ~(size_t)255;
    return p;
  };
  uint* counts   = (uint*)alloc((size_t)nN * 4);
  uint* cursor   = (uint*)alloc((size_t)nN * 4);
  uint* row_ptr  = (uint*)alloc(((size_t)nN + 1) * 4);
  uint* blk_sums = (uint*)alloc((size_t)nBlk * 4);
  uint* blk_offs = (uint*)alloc((size_t)nBlk * 4);
  uint* row_s    = (uint*)alloc((size_t)nE * 4);
  uint* col_s    = (uint*)alloc((size_t)nE * 4);
  float* sim0    = (float*)alloc((size_t)nE * 4);   // layer-1 mask = sim0 > 0
  float* sim1    = (float*)alloc((size_t)nE * 4);
  float* nrm0    = (float*)alloc((size_t)nN * 4);
  float* nrm1    = (float*)alloc((size_t)nN * 4);
  float* rowsum0 = (float*)alloc((size_t)nN * 4);
  float* rowsum1 = (float*)alloc((size_t)nN * 4);
  float* wself0  = (float*)alloc((size_t)nN * 4);
  float* wself1  = (float*)alloc((size_t)nN * 4);
  float* Wt0     = (float*)alloc((size_t)D_IN * D_H * 4);
  float* Wt1     = (float*)alloc((size_t)D_H * D_O * 4);
  float* hbuf    = (float*)alloc((size_t)nN * D_H * 4);
  float* x1      = (float*)alloc((size_t)nN * D_H * 4);

  hipMemsetAsync(counts, 0, (size_t)nN * 4, stream);

  node_norm_kernel<<<(nN * 64 + 255) / 256, 256, 0, stream>>>(x, nrm0, nN);
  hist_kernel<<<(nE + 255) / 256, 256, 0, stream>>>(erow, counts, nE);
  block_scan_kernel<<<nBlk, 256, 0, stream>>>(counts, row_ptr, blk_sums, nN);
  scan_sums_kernel<<<1, 256, 0, stream>>>(blk_sums, blk_offs, nBlk);
  add_offs_kernel<<<nBlk, 256, 0, stream>>>(row_ptr, cursor, blk_offs, nN, (uint)nE);
  scatter_kernel<<<(nE + 255) / 256, 256, 0, stream>>>(erow, ecol, cursor, row_s, col_s, nE);
  transpose_kernel<<<(D_H * D_IN + 255) / 256, 256, 0, stream>>>(W0, Wt0, D_H, D_IN);
  transpose_kernel<<<(D_O * D_H + 255) / 256, 256, 0, stream>>>(W1, Wt1, D_O, D_H);

  // layer 0
  att_kernel<false><<<(nE + 63) / 64, 256, 0, stream>>>(x, nrm0, row_s, col_s, nullptr, sim0, nE);
  rowdeg_kernel<<<(nN + 255) / 256, 256, 0, stream>>>(sim0, row_ptr, rowsum0, wself0, nN);
  gemm_kernel<D_H><<<dim3((nN + 63) / 64, D_H / 64), 256, 0, stream>>>(x, Wt0, b0, hbuf, nN);
  spmm_kernel<D_H, true, true><<<(nN * 64 + 255) / 256, 256, 0, stream>>>(
      hbuf, sim0, col_s, row_ptr, rowsum0, wself0, x1, nrm1, nN);

  // layer 1 (mask = active edges of layer 0)
  att_kernel<true><<<(nE + 63) / 64, 256, 0, stream>>>(x1, nrm1, row_s, col_s, sim0, sim1, nE);
  rowdeg_kernel<<<(nN + 255) / 256, 256, 0, stream>>>(sim1, row_ptr, rowsum1, wself1, nN);
  gemm_kernel<D_O><<<dim3((nN + 63) / 64, 1), 256, 0, stream>>>(x1, Wt1, b1, hbuf, nN);
  spmm_kernel<D_O, false, false><<<(nN * 64 + 255) / 256, 256, 0, stream>>>(
      hbuf, sim1, col_s, row_ptr, rowsum1, wself1, out, nullptr, nN);
}

// Round 7
// 469.100 us; speedup vs baseline: 1.0393x; 1.0393x over previous
//
#include <hip/hip_runtime.h>
#include <math.h>

// GCNGuard forward: 2 layers of {cosine-sim edge attention -> linear -> SPMM}.
// R3: multi-block scan (113us -> ~4us).
// R4: 4 edges per 16-lane subgroup for 4x gather MLP -- REGRESSED: divergent
//     branch writing r[4]/c[4]/d[4] arrays defeated SROA -> PromoteAlloca put
//     them in LDS (LDS_Block_Size=12288, 600K bank conflicts, VALUBusy 17%).
// R6: same structure, FULLY SCALARIZED (named scalars + named float4 payloads,
//     ?:-chain epilogue) so everything stays in VGPRs.

constexpr int D_IN = 128;
constexpr int D_H  = 128;
constexpr int D_O  = 64;

typedef unsigned int uint;

// ---------------- node norms: one wave per node (D=128, 2 floats/lane) -------
__global__ __launch_bounds__(256) void node_norm_kernel(
    const float* __restrict__ x, float* __restrict__ nrm, int n) {
  int gid = blockIdx.x * blockDim.x + threadIdx.x;
  int i = gid >> 6;
  if (i >= n) return;
  int l = threadIdx.x & 63;
  float2 v = *reinterpret_cast<const float2*>(x + (size_t)i * 128 + l * 2);
  float s = v.x * v.x + v.y * v.y;
#pragma unroll
  for (int m = 1; m < 64; m <<= 1) s += __shfl_xor(s, m);
  if (l == 0) nrm[i] = sqrtf(s);
}

// ---------------- CSR build --------------------------------------------------
__global__ __launch_bounds__(256) void hist_kernel(
    const int* __restrict__ row, uint* __restrict__ counts, int nE) {
  int e = blockIdx.x * blockDim.x + threadIdx.x;
  if (e < nE) atomicAdd(&counts[row[e]], 1u);
}

// phase 1: per-block exclusive scan of 256 counts, emit block sum
__global__ __launch_bounds__(256) void block_scan_kernel(
    const uint* __restrict__ counts, uint* __restrict__ row_excl,
    uint* __restrict__ blk_sums, int n) {
  __shared__ uint sh[256];
  int t = threadIdx.x;
  int i = blockIdx.x * 256 + t;
  uint v = (i < n) ? counts[i] : 0u;
  sh[t] = v;
  __syncthreads();
#pragma unroll
  for (int off = 1; off < 256; off <<= 1) {
    uint u = (t >= off) ? sh[t - off] : 0u;
    __syncthreads();
    sh[t] += u;
    __syncthreads();
  }
  if (i < n) row_excl[i] = sh[t] - v;         // exclusive-in-block
  if (t == 255) blk_sums[blockIdx.x] = sh[255];
}

// phase 2: scan the block sums (nb <= 256) in one small block
__global__ __launch_bounds__(256) void scan_sums_kernel(
    const uint* __restrict__ blk_sums, uint* __restrict__ blk_offs, int nb) {
  __shared__ uint sh[256];
  int t = threadIdx.x;
  uint v = (t < nb) ? blk_sums[t] : 0u;
  sh[t] = v;
  __syncthreads();
#pragma unroll
  for (int off = 1; off < 256; off <<= 1) {
    uint u = (t >= off) ? sh[t - off] : 0u;
    __syncthreads();
    sh[t] += u;
    __syncthreads();
  }
  if (t < nb) blk_offs[t] = sh[t] - v;        // exclusive block offset
}

// phase 3: add block offsets, materialize row_ptr + cursor, cap row_ptr[n]
__global__ __launch_bounds__(256) void add_offs_kernel(
    uint* __restrict__ row_ptr, uint* __restrict__ cursor,
    const uint* __restrict__ blk_offs, int n, uint nE) {
  int i = blockIdx.x * 256 + threadIdx.x;
  if (i < n) {
    uint v = row_ptr[i] + blk_offs[blockIdx.x];
    row_ptr[i] = v;
    cursor[i] = v;
  }
  if (i == n) row_ptr[n] = nE;                // grid over-covers by <256
}

__global__ __launch_bounds__(256) void scatter_kernel(
    const int* __restrict__ row, const int* __restrict__ col,
    uint* __restrict__ cursor, uint* __restrict__ row_s,
    uint* __restrict__ col_s, int nE) {
  int e = blockIdx.x * blockDim.x + threadIdx.x;
  if (e >= nE) return;
  int r = row[e];
  uint p = atomicAdd(&cursor[r], 1u);
  row_s[p] = (uint)r;
  col_s[p] = (uint)col[e];
}

// ---------------- W transpose (once per call, tiny) --------------------------
__global__ __launch_bounds__(256) void transpose_kernel(
    const float* __restrict__ W, float* __restrict__ Wt, int J, int K) {
  int idx = blockIdx.x * blockDim.x + threadIdx.x;
  if (idx >= J * K) return;
  int j = idx >> 7;        // K == 128 always here
  int k = idx & 127;
  Wt[k * J + j] = W[idx];
}

// ---------------- attention SDDMM: 4 edges per 16-lane subgroup --------------
// Fully scalarized: 16 independent dwordx4 gathers in VGPRs, no arrays.
template <bool MASKED>
__global__ __launch_bounds__(256) void att_kernel(
    const float* __restrict__ x, const float* __restrict__ nrm,
    const uint* __restrict__ row_s, const uint* __restrict__ col_s,
    const float* __restrict__ mask_sim, float* __restrict__ sim_out, int nE) {
  int sg = threadIdx.x >> 4;
  int sl = threadIdx.x & 15;
  int p0 = (blockIdx.x * 16 + sg) * 4;
  if (p0 >= nE) return;

  uint r0, r1, r2, r3, c0, c1, c2, c3;
  if (p0 + 3 < nE) {                       // vector idx load (16B-aligned)
    uint4 rr = *reinterpret_cast<const uint4*>(row_s + p0);
    uint4 cc = *reinterpret_cast<const uint4*>(col_s + p0);
    r0 = rr.x; r1 = rr.y; r2 = rr.z; r3 = rr.w;
    c0 = cc.x; c1 = cc.y; c2 = cc.z; c3 = cc.w;
  } else {
    int q1 = (p0 + 1 < nE) ? p0 + 1 : p0;
    int q2 = (p0 + 2 < nE) ? p0 + 2 : p0;
    int q3 = (p0 + 3 < nE) ? p0 + 3 : p0;
    r0 = row_s[p0]; r1 = row_s[q1]; r2 = row_s[q2]; r3 = row_s[q3];
    c0 = col_s[p0]; c1 = col_s[q1]; c2 = col_s[q2]; c3 = col_s[q3];
  }

  const float4* xr0 = reinterpret_cast<const float4*>(x + (size_t)r0 * 128);
  const float4* xr1 = reinterpret_cast<const float4*>(x + (size_t)r1 * 128);
  const float4* xr2 = reinterpret_cast<const float4*>(x + (size_t)r2 * 128);
  const float4* xr3 = reinterpret_cast<const float4*>(x + (size_t)r3 * 128);
  const float4* xc0 = reinterpret_cast<const float4*>(x + (size_t)c0 * 128);
  const float4* xc1 = reinterpret_cast<const float4*>(x + (size_t)c1 * 128);
  const float4* xc2 = reinterpret_cast<const float4*>(x + (size_t)c2 * 128);
  const float4* xc3 = reinterpret_cast<const float4*>(x + (size_t)c3 * 128);
  int o0 = sl * 2, o1 = sl * 2 + 1;

  float4 a00 = xr0[o0], a01 = xr0[o1];     // 16 independent dwordx4 loads
  float4 a10 = xr1[o0], a11 = xr1[o1];
  float4 a20 = xr2[o0], a21 = xr2[o1];
  float4 a30 = xr3[o0], a31 = xr3[o1];
  float4 b00 = xc0[o0], b01 = xc0[o1];
  float4 b10 = xc1[o0], b11 = xc1[o1];
  float4 b20 = xc2[o0], b21 = xc2[o1];
  float4 b30 = xc3[o0], b31 = xc3[o1];

  float d0 = a00.x * b00.x + a00.y * b00.y + a00.z * b00.z + a00.w * b00.w +
             a01.x * b01.x + a01.y * b01.y + a01.z * b01.z + a01.w * b01.w;
  float d1 = a10.x * b10.x + a10.y * b10.y + a10.z * b10.z + a10.w * b10.w +
             a11.x * b11.x + a11.y * b11.y + a11.z * b11.z + a11.w * b11.w;
  float d2 = a20.x * b20.x + a20.y * b20.y + a20.z * b20.z + a20.w * b20.w +
             a21.x * b21.x + a21.y * b21.y + a21.z * b21.z + a21.w * b21.w;
  float d3 = a30.x * b30.x + a30.y * b30.y + a30.z * b30.z + a30.w * b30.w +
             a31.x * b31.x + a31.y * b31.y + a31.z * b31.z + a31.w * b31.w;

#pragma unroll
  for (int m = 1; m <= 8; m <<= 1) {
    d0 += __shfl_xor(d0, m);
    d1 += __shfl_xor(d1, m);
    d2 += __shfl_xor(d2, m);
    d3 += __shfl_xor(d3, m);
  }

  // epilogue on lanes 0..3, one edge each (?:-chains -> cndmask, no scratch)
  float dv = (sl == 1) ? d1 : (sl == 2) ? d2 : (sl == 3) ? d3 : d0;
  uint  rv = (sl == 1) ? r1 : (sl == 2) ? r2 : (sl == 3) ? r3 : r0;
  uint  cv = (sl == 1) ? c1 : (sl == 2) ? c2 : (sl == 3) ? c3 : c0;
  if (sl < 4 && p0 + sl < nE) {
    float sim = dv / fmaxf(nrm[rv] * nrm[cv], 1e-12f);
    bool ok = (sim >= 0.1f);
    if (MASKED) ok = ok && (mask_sim[p0 + sl] > 0.0f);
    sim_out[p0 + sl] = ok ? sim : 0.0f;
  }
}

// ---------------- per-row sums + self-loop weight ---------------------------
__global__ __launch_bounds__(256) void rowdeg_kernel(
    const float* __restrict__ sim_s, const uint* __restrict__ row_ptr,
    float* __restrict__ rowsum, float* __restrict__ wself, int n) {
  int i = blockIdx.x * blockDim.x + threadIdx.x;
  if (i >= n) return;
  uint p0 = row_ptr[i], p1 = row_ptr[i + 1];
  float s = 0.f, d = 0.f;
  for (uint p = p0; p < p1; ++p) {
    float v = sim_s[p];
    s += v;
    if (v > 0.f) d += 1.f;
  }
  rowsum[i] = s;
  wself[i] = expf(1.0f / (d + 1.0f));
}

// ---------------- f32 GEMM: H[M][DOUT] = X[M][128] @ Wt[128][DOUT] + b ------
// 64x64 tile, 4x4 register blocking, conflict-free LDS read paths.
template <int DOUT>
__global__ __launch_bounds__(256) void gemm_kernel(
    const float* __restrict__ X, const float* __restrict__ Wt,
    const float* __restrict__ bias, float* __restrict__ H, int M) {
  __shared__ float xs[64][132];   // +4 pad: a-reads land 2-way (free)
  __shared__ float wl[128][64];   // [k][j], staged linearly -> conflict-free
  int i0 = blockIdx.x * 64;
  int j0 = blockIdx.y * 64;
  int t = threadIdx.x;
#pragma unroll
  for (int it = 0; it < 8; ++it) {           // stage W block: 2048 float4
    int idx = it * 256 + t;
    int k = idx >> 4, jq = idx & 15;
    float4 v = *reinterpret_cast<const float4*>(Wt + (size_t)k * DOUT + j0 + jq * 4);
    *reinterpret_cast<float4*>(&wl[k][jq * 4]) = v;
  }
#pragma unroll
  for (int it = 0; it < 8; ++it) {           // stage X tile: 64 rows x 128
    int i = it * 8 + (t >> 5);
    int kq = t & 31;
    int row = i0 + i;
    float4 v = make_float4(0.f, 0.f, 0.f, 0.f);
    if (row < M) v = *reinterpret_cast<const float4*>(X + (size_t)row * 128 + kq * 4);
    *reinterpret_cast<float4*>(&xs[i][kq * 4]) = v;
  }
  __syncthreads();
  int cg = t & 15, rg = t >> 4;
  int r0 = rg * 4, c0 = cg * 4;
  float acc[4][4] = {};
#pragma unroll 8
  for (int k = 0; k < 128; ++k) {
    float4 b4 = *reinterpret_cast<const float4*>(&wl[k][c0]);
    float a0 = xs[r0 + 0][k], a1 = xs[r0 + 1][k];
    float a2 = xs[r0 + 2][k], a3 = xs[r0 + 3][k];
    acc[0][0] += a0 * b4.x; acc[0][1] += a0 * b4.y; acc[0][2] += a0 * b4.z; acc[0][3] += a0 * b4.w;
    acc[1][0] += a1 * b4.x; acc[1][1] += a1 * b4.y; acc[1][2] += a1 * b4.z; acc[1][3] += a1 * b4.w;
    acc[2][0] += a2 * b4.x; acc[2][1] += a2 * b4.y; acc[2][2] += a2 * b4.z; acc[2][3] += a2 * b4.w;
    acc[3][0] += a3 * b4.x; acc[3][1] += a3 * b4.y; acc[3][2] += a3 * b4.z; acc[3][3] += a3 * b4.w;
  }
  float4 bb = *reinterpret_cast<const float4*>(bias + j0 + c0);
#pragma unroll
  for (int r = 0; r < 4; ++r) {
    int row = i0 + r0 + r;
    if (row < M) {
      float4 o = make_float4(acc[r][0] + bb.x, acc[r][1] + bb.y,
                             acc[r][2] + bb.z, acc[r][3] + bb.w);
      *reinterpret_cast<float4*>(H + (size_t)row * DOUT + j0 + c0) = o;
    }
  }
}

// ---------------- SPMM: wave per row, register accum, fused epilogue --------
template <int D, bool RELU, bool WRITE_NORM>
__global__ __launch_bounds__(256) void spmm_kernel(
    const float* __restrict__ H, const float* __restrict__ sim_s,
    const uint* __restrict__ col_s, const uint* __restrict__ row_ptr,
    const float* __restrict__ rowsum, const float* __restrict__ wself,
    float* __restrict__ out, float* __restrict__ norm_out, int n) {
  int gid = blockIdx.x * blockDim.x + threadIdx.x;
  int i = gid >> 6;
  if (i >= n) return;
  int l = threadIdx.x & 63;
  float ws = wself[i];
  float inv = 1.0f / fmaxf(rowsum[i], 1e-30f);
  uint p1 = row_ptr[i + 1];

  if constexpr (D == 128) {
    float2 hv = *reinterpret_cast<const float2*>(H + (size_t)i * 128 + l * 2);
    float ax = ws * hv.x, ay = ws * hv.y;
    for (uint p = row_ptr[i]; p < p1; ++p) {
      float s = sim_s[p];
      if (s > 0.0f) {                       // wave-uniform branch
        float w = expf(s * inv);
        uint c = col_s[p];
        float2 hc = *reinterpret_cast<const float2*>(H + (size_t)c * 128 + l * 2);
        ax += w * hc.x;
        ay += w * hc.y;
      }
    }
    if (RELU) { ax = fmaxf(ax, 0.f); ay = fmaxf(ay, 0.f); }
    float2 o; o.x = ax; o.y = ay;
    *reinterpret_cast<float2*>(out + (size_t)i * 128 + l * 2) = o;
    if (WRITE_NORM) {
      float s = ax * ax + ay * ay;
#pragma unroll
      for (int m = 1; m < 64; m <<= 1) s += __shfl_xor(s, m);
      if (l == 0) norm_out[i] = sqrtf(s);
    }
  } else {  // D == 64
    float a = ws * H[(size_t)i * 64 + l];
    for (uint p = row_ptr[i]; p < p1; ++p) {
      float s = sim_s[p];
      if (s > 0.0f) {
        float w = expf(s * inv);
        uint c = col_s[p];
        a += w * H[(size_t)c * 64 + l];
      }
    }
    if (RELU) a = fmaxf(a, 0.f);
    out[(size_t)i * 64 + l] = a;
    if (WRITE_NORM) {
      float s = a * a;
#pragma unroll
      for (int m = 1; m < 64; m <<= 1) s += __shfl_xor(s, m);
      if (l == 0) norm_out[i] = sqrtf(s);
    }
  }
}

// ---------------- launch -----------------------------------------------------
extern "C" void kernel_launch(void* const* d_in, const int* in_sizes, int n_in,
                              void* d_out, int out_size, void* d_ws, size_t ws_size,
                              hipStream_t stream) {
  const float* x  = (const float*)d_in[0];
  const float* W0 = (const float*)d_in[1];
  const float* b0 = (const float*)d_in[2];
  const float* W1 = (const float*)d_in[3];
  const float* b1 = (const float*)d_in[4];
  const int* erow = (const int*)d_in[5];
  const int* ecol = (const int*)d_in[6];
  float* out = (float*)d_out;

  int nN = in_sizes[0] / D_IN;  // 50000
  int nE = in_sizes[5];         // 800000
  int nBlk = (nN + 255) / 256;  // 196 scan blocks

  char* w = (char*)d_ws;
  auto alloc = [&](size_t bytes) {
    char* p = w;
    w += (bytes + 255) & ~(size_t)255;
    return p;
  };
  uint* counts   = (uint*)alloc((size_t)nN * 4);
  uint* cursor   = (uint*)alloc((size_t)nN * 4);
  uint* row_ptr  = (uint*)alloc(((size_t)nN + 1) * 4);
  uint* blk_sums = (uint*)alloc((size_t)nBlk * 4);
  uint* blk_offs = (uint*)alloc((size_t)nBlk * 4);
  uint* row_s    = (uint*)alloc((size_t)nE * 4);
  uint* col_s    = (uint*)alloc((size_t)nE * 4);
  float* sim0    = (float*)alloc((size_t)nE * 4);   // layer-1 mask = sim0 > 0
  float* sim1    = (float*)alloc((size_t)nE * 4);
  float* nrm0    = (float*)alloc((size_t)nN * 4);
  float* nrm1    = (float*)alloc((size_t)nN * 4);
  float* rowsum0 = (float*)alloc((size_t)nN * 4);
  float* rowsum1 = (float*)alloc((size_t)nN * 4);
  float* wself0  = (float*)alloc((size_t)nN * 4);
  float* wself1  = (float*)alloc((size_t)nN * 4);
  float* Wt0     = (float*)alloc((size_t)D_IN * D_H * 4);
  float* Wt1     = (float*)alloc((size_t)D_H * D_O * 4);
  float* hbuf    = (float*)alloc((size_t)nN * D_H * 4);
  float* x1      = (float*)alloc((size_t)nN * D_H * 4);

  hipMemsetAsync(counts, 0, (size_t)nN * 4, stream);

  node_norm_kernel<<<(nN * 64 + 255) / 256, 256, 0, stream>>>(x, nrm0, nN);
  hist_kernel<<<(nE + 255) / 256, 256, 0, stream>>>(erow, counts, nE);
  block_scan_kernel<<<nBlk, 256, 0, stream>>>(counts, row_ptr, blk_sums, nN);
  scan_sums_kernel<<<1, 256, 0, stream>>>(blk_sums, blk_offs, nBlk);
  add_offs_kernel<<<nBlk, 256, 0, stream>>>(row_ptr, cursor, blk_offs, nN, (uint)nE);
  scatter_kernel<<<(nE + 255) / 256, 256, 0, stream>>>(erow, ecol, cursor, row_s, col_s, nE);
  transpose_kernel<<<(D_H * D_IN + 255) / 256, 256, 0, stream>>>(W0, Wt0, D_H, D_IN);
  transpose_kernel<<<(D_O * D_H + 255) / 256, 256, 0, stream>>>(W1, Wt1, D_O, D_H);

  // layer 0
  att_kernel<false><<<(nE + 63) / 64, 256, 0, stream>>>(x, nrm0, row_s, col_s, nullptr, sim0, nE);
  rowdeg_kernel<<<(nN + 255) / 256, 256, 0, stream>>>(sim0, row_ptr, rowsum0, wself0, nN);
  gemm_kernel<D_H><<<dim3((nN + 63) / 64, D_H / 64), 256, 0, stream>>>(x, Wt0, b0, hbuf, nN);
  spmm_kernel<D_H, true, true><<<(nN * 64 + 255) / 256, 256, 0, stream>>>(
      hbuf, sim0, col_s, row_ptr, rowsum0, wself0, x1, nrm1, nN);

  // layer 1 (mask = active edges of layer 0)
  att_kernel<true><<<(nE + 63) / 64, 256, 0, stream>>>(x1, nrm1, row_s, col_s, sim0, sim1, nE);
  rowdeg_kernel<<<(nN + 255) / 256, 256, 0, stream>>>(sim1, row_ptr, rowsum1, wself1, nN);
  gemm_kernel<D_O><<<dim3((nN + 63) / 64, 1), 256, 0, stream>>>(x1, Wt1, b1, hbuf, nN);
  spmm_kernel<D_O, false, false><<<(nN * 64 + 255) / 256, 256, 0, stream>>>(
      hbuf, sim1, col_s, row_ptr, rowsum1, wself1, out, nullptr, nN);
}

// Round 9
// 391.318 us; speedup vs baseline: 1.2459x; 1.1988x over previous
//
#include <hip/hip_runtime.h>
#include <math.h>

// GCNGuard forward: 2 layers of {cosine-sim edge attention -> linear -> SPMM}.
// R3: multi-block scan (113us -> ~4us).
// R4/R6: att 4 edges/subgroup, fully scalarized (LDS-promotion trap fixed).
// R7: ACTIVE-EDGE COMPACTION. Only ~13% of edges pass sim>=0.1; build dense
//     (row,col,w=exp(sim/rowsum)) lists per layer so spmm is branch-free over
//     active edges only and att1 runs on the compacted list (~104k not 800k).

constexpr int D_IN = 128;
constexpr int D_H  = 128;
constexpr int D_O  = 64;

typedef unsigned int uint;

// ---------------- node norms: one wave per node (D=128, 2 floats/lane) -------
__global__ __launch_bounds__(256) void node_norm_kernel(
    const float* __restrict__ x, float* __restrict__ nrm, int n) {
  int gid = blockIdx.x * blockDim.x + threadIdx.x;
  int i = gid >> 6;
  if (i >= n) return;
  int l = threadIdx.x & 63;
  float2 v = *reinterpret_cast<const float2*>(x + (size_t)i * 128 + l * 2);
  float s = v.x * v.x + v.y * v.y;
#pragma unroll
  for (int m = 1; m < 64; m <<= 1) s += __shfl_xor(s, m);
  if (l == 0) nrm[i] = sqrtf(s);
}

// ---------------- CSR build --------------------------------------------------
__global__ __launch_bounds__(256) void hist_kernel(
    const int* __restrict__ row, uint* __restrict__ counts, int nE) {
  int e = blockIdx.x * blockDim.x + threadIdx.x;
  if (e < nE) atomicAdd(&counts[row[e]], 1u);
}

// phase 1: per-block exclusive scan of 256 counts, emit block sum
__global__ __launch_bounds__(256) void block_scan_kernel(
    const uint* __restrict__ counts, uint* __restrict__ row_excl,
    uint* __restrict__ blk_sums, int n) {
  __shared__ uint sh[256];
  int t = threadIdx.x;
  int i = blockIdx.x * 256 + t;
  uint v = (i < n) ? counts[i] : 0u;
  sh[t] = v;
  __syncthreads();
#pragma unroll
  for (int off = 1; off < 256; off <<= 1) {
    uint u = (t >= off) ? sh[t - off] : 0u;
    __syncthreads();
    sh[t] += u;
    __syncthreads();
  }
  if (i < n) row_excl[i] = sh[t] - v;         // exclusive-in-block
  if (t == 255) blk_sums[blockIdx.x] = sh[255];
}

// phase 2: scan the block sums (nb <= 256) in one small block
__global__ __launch_bounds__(256) void scan_sums_kernel(
    const uint* __restrict__ blk_sums, uint* __restrict__ blk_offs, int nb) {
  __shared__ uint sh[256];
  int t = threadIdx.x;
  uint v = (t < nb) ? blk_sums[t] : 0u;
  sh[t] = v;
  __syncthreads();
#pragma unroll
  for (int off = 1; off < 256; off <<= 1) {
    uint u = (t >= off) ? sh[t - off] : 0u;
    __syncthreads();
    sh[t] += u;
    __syncthreads();
  }
  if (t < nb) blk_offs[t] = sh[t] - v;        // exclusive block offset
}

// phase 3: add block offsets; rp[n] = grand total; optional cursor copy
__global__ __launch_bounds__(256) void add_offs_kernel(
    uint* __restrict__ rp, uint* __restrict__ cursor,
    const uint* __restrict__ blk_offs, const uint* __restrict__ blk_sums,
    int n, int nb) {
  int i = blockIdx.x * 256 + threadIdx.x;
  if (i < n) {
    uint v = rp[i] + blk_offs[blockIdx.x];
    rp[i] = v;
    if (cursor) cursor[i] = v;
  }
  if (i == n) rp[n] = blk_offs[nb - 1] + blk_sums[nb - 1];
}

__global__ __launch_bounds__(256) void scatter_kernel(
    const int* __restrict__ row, const int* __restrict__ col,
    uint* __restrict__ cursor, uint* __restrict__ row_s,
    uint* __restrict__ col_s, int nE) {
  int e = blockIdx.x * blockDim.x + threadIdx.x;
  if (e >= nE) return;
  int r = row[e];
  uint p = atomicAdd(&cursor[r], 1u);
  row_s[p] = (uint)r;
  col_s[p] = (uint)col[e];
}

// ---------------- W transpose (once per call, tiny) --------------------------
__global__ __launch_bounds__(256) void transpose_kernel(
    const float* __restrict__ W, float* __restrict__ Wt, int J, int K) {
  int idx = blockIdx.x * blockDim.x + threadIdx.x;
  if (idx >= J * K) return;
  int j = idx >> 7;        // K == 128 always here
  int k = idx & 127;
  Wt[k * J + j] = W[idx];
}

// ---------------- attention SDDMM: 4 edges per 16-lane subgroup --------------
// Fully scalarized (R6). nE_dyn (if non-null) overrides nE_static for
// compacted-list invocation (value = rptr_a[nN], only known on device).
__global__ __launch_bounds__(256) void att_kernel(
    const float* __restrict__ x, const float* __restrict__ nrm,
    const uint* __restrict__ rows, const uint* __restrict__ cols,
    float* __restrict__ sim_out, int nE_static,
    const uint* __restrict__ nE_dyn) {
  int nE = nE_dyn ? (int)*nE_dyn : nE_static;
  int sg = threadIdx.x >> 4;
  int sl = threadIdx.x & 15;
  int p0 = (blockIdx.x * 16 + sg) * 4;
  if (p0 >= nE) return;

  uint r0, r1, r2, r3, c0, c1, c2, c3;
  if (p0 + 3 < nE) {                       // vector idx load (16B-aligned)
    uint4 rr = *reinterpret_cast<const uint4*>(rows + p0);
    uint4 cc = *reinterpret_cast<const uint4*>(cols + p0);
    r0 = rr.x; r1 = rr.y; r2 = rr.z; r3 = rr.w;
    c0 = cc.x; c1 = cc.y; c2 = cc.z; c3 = cc.w;
  } else {
    int q1 = (p0 + 1 < nE) ? p0 + 1 : p0;
    int q2 = (p0 + 2 < nE) ? p0 + 2 : p0;
    int q3 = (p0 + 3 < nE) ? p0 + 3 : p0;
    r0 = rows[p0]; r1 = rows[q1]; r2 = rows[q2]; r3 = rows[q3];
    c0 = cols[p0]; c1 = cols[q1]; c2 = cols[q2]; c3 = cols[q3];
  }

  const float4* xr0 = reinterpret_cast<const float4*>(x + (size_t)r0 * 128);
  const float4* xr1 = reinterpret_cast<const float4*>(x + (size_t)r1 * 128);
  const float4* xr2 = reinterpret_cast<const float4*>(x + (size_t)r2 * 128);
  const float4* xr3 = reinterpret_cast<const float4*>(x + (size_t)r3 * 128);
  const float4* xc0 = reinterpret_cast<const float4*>(x + (size_t)c0 * 128);
  const float4* xc1 = reinterpret_cast<const float4*>(x + (size_t)c1 * 128);
  const float4* xc2 = reinterpret_cast<const float4*>(x + (size_t)c2 * 128);
  const float4* xc3 = reinterpret_cast<const float4*>(x + (size_t)c3 * 128);
  int o0 = sl * 2, o1 = sl * 2 + 1;

  float4 a00 = xr0[o0], a01 = xr0[o1];     // 16 independent dwordx4 loads
  float4 a10 = xr1[o0], a11 = xr1[o1];
  float4 a20 = xr2[o0], a21 = xr2[o1];
  float4 a30 = xr3[o0], a31 = xr3[o1];
  float4 b00 = xc0[o0], b01 = xc0[o1];
  float4 b10 = xc1[o0], b11 = xc1[o1];
  float4 b20 = xc2[o0], b21 = xc2[o1];
  float4 b30 = xc3[o0], b31 = xc3[o1];

  float d0 = a00.x * b00.x + a00.y * b00.y + a00.z * b00.z + a00.w * b00.w +
             a01.x * b01.x + a01.y * b01.y + a01.z * b01.z + a01.w * b01.w;
  float d1 = a10.x * b10.x + a10.y * b10.y + a10.z * b10.z + a10.w * b10.w +
             a11.x * b11.x + a11.y * b11.y + a11.z * b11.z + a11.w * b11.w;
  float d2 = a20.x * b20.x + a20.y * b20.y + a20.z * b20.z + a20.w * b20.w +
             a21.x * b21.x + a21.y * b21.y + a21.z * b21.z + a21.w * b21.w;
  float d3 = a30.x * b30.x + a30.y * b30.y + a30.z * b30.z + a30.w * b30.w +
             a31.x * b31.x + a31.y * b31.y + a31.z * b31.z + a31.w * b31.w;

#pragma unroll
  for (int m = 1; m <= 8; m <<= 1) {
    d0 += __shfl_xor(d0, m);
    d1 += __shfl_xor(d1, m);
    d2 += __shfl_xor(d2, m);
    d3 += __shfl_xor(d3, m);
  }

  // epilogue on lanes 0..3, one edge each (?:-chains -> cndmask, no scratch)
  float dv = (sl == 1) ? d1 : (sl == 2) ? d2 : (sl == 3) ? d3 : d0;
  uint  rv = (sl == 1) ? r1 : (sl == 2) ? r2 : (sl == 3) ? r3 : r0;
  uint  cv = (sl == 1) ? c1 : (sl == 2) ? c2 : (sl == 3) ? c3 : c0;
  if (sl < 4 && p0 + sl < nE) {
    float sim = dv / fmaxf(nrm[rv] * nrm[cv], 1e-12f);
    sim_out[p0 + sl] = (sim >= 0.1f) ? sim : 0.0f;
  }
}

// ---------------- per-row sums + active count + self-loop weight ------------
__global__ __launch_bounds__(256) void rowdeg_kernel(
    const float* __restrict__ sim_s, const uint* __restrict__ rp,
    float* __restrict__ rowsum, float* __restrict__ wself,
    uint* __restrict__ cnt, int n) {
  int i = blockIdx.x * blockDim.x + threadIdx.x;
  if (i >= n) return;
  uint p0 = rp[i], p1 = rp[i + 1];
  float s = 0.f;
  uint d = 0;
  for (uint p = p0; p < p1; ++p) {
    float v = sim_s[p];
    s += v;
    if (v > 0.f) ++d;
  }
  rowsum[i] = s;
  wself[i] = expf(1.0f / ((float)d + 1.0f));
  cnt[i] = d;
}

// ---------------- compact: dense active lists, row-owned segments -----------
__global__ __launch_bounds__(256) void compact_kernel(
    const float* __restrict__ sim_s, const uint* __restrict__ col_in,
    const uint* __restrict__ rp_in, const float* __restrict__ rowsum,
    const uint* __restrict__ rp_out, uint* __restrict__ row_out,
    uint* __restrict__ col_out, float* __restrict__ w_out, int n) {
  int i = blockIdx.x * blockDim.x + threadIdx.x;
  if (i >= n) return;
  uint q = rp_out[i];
  uint p1 = rp_in[i + 1];
  float inv = 1.0f / fmaxf(rowsum[i], 1e-30f);
  for (uint p = rp_in[i]; p < p1; ++p) {
    float s = sim_s[p];
    if (s > 0.0f) {
      col_out[q] = col_in[p];
      w_out[q] = expf(s * inv);
      if (row_out) row_out[q] = (uint)i;
      ++q;
    }
  }
}

// ---------------- f32 GEMM: H[M][DOUT] = X[M][128] @ Wt[128][DOUT] + b ------
template <int DOUT>
__global__ __launch_bounds__(256) void gemm_kernel(
    const float* __restrict__ X, const float* __restrict__ Wt,
    const float* __restrict__ bias, float* __restrict__ H, int M) {
  __shared__ float xs[64][132];   // +4 pad: a-reads land 2-way (free)
  __shared__ float wl[128][64];   // [k][j], staged linearly -> conflict-free
  int i0 = blockIdx.x * 64;
  int j0 = blockIdx.y * 64;
  int t = threadIdx.x;
#pragma unroll
  for (int it = 0; it < 8; ++it) {           // stage W block: 2048 float4
    int idx = it * 256 + t;
    int k = idx >> 4, jq = idx & 15;
    float4 v = *reinterpret_cast<const float4*>(Wt + (size_t)k * DOUT + j0 + jq * 4);
    *reinterpret_cast<float4*>(&wl[k][jq * 4]) = v;
  }
#pragma unroll
  for (int it = 0; it < 8; ++it) {           // stage X tile: 64 rows x 128
    int i = it * 8 + (t >> 5);
    int kq = t & 31;
    int row = i0 + i;
    float4 v = make_float4(0.f, 0.f, 0.f, 0.f);
    if (row < M) v = *reinterpret_cast<const float4*>(X + (size_t)row * 128 + kq * 4);
    *reinterpret_cast<float4*>(&xs[i][kq * 4]) = v;
  }
  __syncthreads();
  int cg = t & 15, rg = t >> 4;
  int r0 = rg * 4, c0 = cg * 4;
  float acc[4][4] = {};
#pragma unroll 8
  for (int k = 0; k < 128; ++k) {
    float4 b4 = *reinterpret_cast<const float4*>(&wl[k][c0]);
    float a0 = xs[r0 + 0][k], a1 = xs[r0 + 1][k];
    float a2 = xs[r0 + 2][k], a3 = xs[r0 + 3][k];
    acc[0][0] += a0 * b4.x; acc[0][1] += a0 * b4.y; acc[0][2] += a0 * b4.z; acc[0][3] += a0 * b4.w;
    acc[1][0] += a1 * b4.x; acc[1][1] += a1 * b4.y; acc[1][2] += a1 * b4.z; acc[1][3] += a1 * b4.w;
    acc[2][0] += a2 * b4.x; acc[2][1] += a2 * b4.y; acc[2][2] += a2 * b4.z; acc[2][3] += a2 * b4.w;
    acc[3][0] += a3 * b4.x; acc[3][1] += a3 * b4.y; acc[3][2] += a3 * b4.z; acc[3][3] += a3 * b4.w;
  }
  float4 bb = *reinterpret_cast<const float4*>(bias + j0 + c0);
#pragma unroll
  for (int r = 0; r < 4; ++r) {
    int row = i0 + r0 + r;
    if (row < M) {
      float4 o = make_float4(acc[r][0] + bb.x, acc[r][1] + bb.y,
                             acc[r][2] + bb.z, acc[r][3] + bb.w);
      *reinterpret_cast<float4*>(H + (size_t)row * DOUT + j0 + c0) = o;
    }
  }
}

// ---------------- SPMM over compacted lists: wave/row, branch-free ----------
template <int D, bool RELU, bool WRITE_NORM>
__global__ __launch_bounds__(256) void spmm_kernel(
    const float* __restrict__ H, const float* __restrict__ w_e,
    const uint* __restrict__ col_e, const uint* __restrict__ rp,
    const float* __restrict__ wself, float* __restrict__ out,
    float* __restrict__ norm_out, int n) {
  int gid = blockIdx.x * blockDim.x + threadIdx.x;
  int i = gid >> 6;
  if (i >= n) return;
  int l = threadIdx.x & 63;
  float ws = wself[i];
  uint p1 = rp[i + 1];

  if constexpr (D == 128) {
    float2 hv = *reinterpret_cast<const float2*>(H + (size_t)i * 128 + l * 2);
    float ax = ws * hv.x, ay = ws * hv.y;
    for (uint p = rp[i]; p < p1; ++p) {
      float w = w_e[p];
      uint c = col_e[p];
      float2 hc = *reinterpret_cast<const float2*>(H + (size_t)c * 128 + l * 2);
      ax += w * hc.x;
      ay += w * hc.y;
    }
    if (RELU) { ax = fmaxf(ax, 0.f); ay = fmaxf(ay, 0.f); }
    float2 o; o.x = ax; o.y = ay;
    *reinterpret_cast<float2*>(out + (size_t)i * 128 + l * 2) = o;
    if (WRITE_NORM) {
      float s = ax * ax + ay * ay;
#pragma unroll
      for (int m = 1; m < 64; m <<= 1) s += __shfl_xor(s, m);
      if (l == 0) norm_out[i] = sqrtf(s);
    }
  } else {  // D == 64
    float a = ws * H[(size_t)i * 64 + l];
    for (uint p = rp[i]; p < p1; ++p) {
      float w = w_e[p];
      uint c = col_e[p];
      a += w * H[(size_t)c * 64 + l];
    }
    if (RELU) a = fmaxf(a, 0.f);
    out[(size_t)i * 64 + l] = a;
    if (WRITE_NORM) {
      float s = a * a;
#pragma unroll
      for (int m = 1; m < 64; m <<= 1) s += __shfl_xor(s, m);
      if (l == 0) norm_out[i] = sqrtf(s);
    }
  }
}

// ---------------- launch -----------------------------------------------------
extern "C" void kernel_launch(void* const* d_in, const int* in_sizes, int n_in,
                              void* d_out, int out_size, void* d_ws, size_t ws_size,
                              hipStream_t stream) {
  const float* x  = (const float*)d_in[0];
  const float* W0 = (const float*)d_in[1];
  const float* b0 = (const float*)d_in[2];
  const float* W1 = (const float*)d_in[3];
  const float* b1 = (const float*)d_in[4];
  const int* erow = (const int*)d_in[5];
  const int* ecol = (const int*)d_in[6];
  float* out = (float*)d_out;

  int nN = in_sizes[0] / D_IN;  // 50000
  int nE = in_sizes[5];         // 800000
  int nBlk = (nN + 255) / 256;  // 196 scan blocks

  char* w = (char*)d_ws;
  auto alloc = [&](size_t bytes) {
    char* p = w;
    w += (bytes + 255) & ~(size_t)255;
    return p;
  };
  uint* counts   = (uint*)alloc((size_t)nN * 4);
  uint* cursor   = (uint*)alloc((size_t)nN * 4);
  uint* row_ptr  = (uint*)alloc(((size_t)nN + 1) * 4);
  uint* blk_sums = (uint*)alloc((size_t)nBlk * 4);
  uint* blk_offs = (uint*)alloc((size_t)nBlk * 4);
  uint* row_s    = (uint*)alloc((size_t)nE * 4);
  uint* col_s    = (uint*)alloc((size_t)nE * 4);
  float* sim     = (float*)alloc((size_t)nE * 4);   // sim0, then simA (layer1)
  float* nrm0    = (float*)alloc((size_t)nN * 4);
  float* nrm1    = (float*)alloc((size_t)nN * 4);
  float* rowsum0 = (float*)alloc((size_t)nN * 4);
  float* rowsum1 = (float*)alloc((size_t)nN * 4);
  float* wself0  = (float*)alloc((size_t)nN * 4);
  float* wself1  = (float*)alloc((size_t)nN * 4);
  uint* cnt_a    = (uint*)alloc((size_t)nN * 4);
  uint* rptr_a   = (uint*)alloc(((size_t)nN + 1) * 4);
  uint* cnt_b    = (uint*)alloc((size_t)nN * 4);
  uint* rptr_b   = (uint*)alloc(((size_t)nN + 1) * 4);
  uint* row_a    = (uint*)alloc((size_t)nE * 4);
  uint* col_a    = (uint*)alloc((size_t)nE * 4);
  float* w_a     = (float*)alloc((size_t)nE * 4);
  float* Wt0     = (float*)alloc((size_t)D_IN * D_H * 4);
  float* Wt1     = (float*)alloc((size_t)D_H * D_O * 4);
  float* hbuf    = (float*)alloc((size_t)nN * D_H * 4);
  float* x1      = (float*)alloc((size_t)nN * D_H * 4);
  // layer-1 compacted lists alias row_s/col_s (dead after att0/compact0)
  uint* col_b    = row_s;
  float* w_b     = (float*)col_s;

  hipMemsetAsync(counts, 0, (size_t)nN * 4, stream);

  node_norm_kernel<<<(nN * 64 + 255) / 256, 256, 0, stream>>>(x, nrm0, nN);
  hist_kernel<<<(nE + 255) / 256, 256, 0, stream>>>(erow, counts, nE);
  block_scan_kernel<<<nBlk, 256, 0, stream>>>(counts, row_ptr, blk_sums, nN);
  scan_sums_kernel<<<1, 256, 0, stream>>>(blk_sums, blk_offs, nBlk);
  add_offs_kernel<<<nBlk, 256, 0, stream>>>(row_ptr, cursor, blk_offs, blk_sums, nN, nBlk);
  scatter_kernel<<<(nE + 255) / 256, 256, 0, stream>>>(erow, ecol, cursor, row_s, col_s, nE);
  transpose_kernel<<<(D_H * D_IN + 255) / 256, 256, 0, stream>>>(W0, Wt0, D_H, D_IN);
  transpose_kernel<<<(D_O * D_H + 255) / 256, 256, 0, stream>>>(W1, Wt1, D_O, D_H);

  // ---- layer 0 ----
  att_kernel<<<(nE + 63) / 64, 256, 0, stream>>>(x, nrm0, row_s, col_s, sim, nE, nullptr);
  rowdeg_kernel<<<(nN + 255) / 256, 256, 0, stream>>>(sim, row_ptr, rowsum0, wself0, cnt_a, nN);
  block_scan_kernel<<<nBlk, 256, 0, stream>>>(cnt_a, rptr_a, blk_sums, nN);
  scan_sums_kernel<<<1, 256, 0, stream>>>(blk_sums, blk_offs, nBlk);
  add_offs_kernel<<<nBlk, 256, 0, stream>>>(rptr_a, nullptr, blk_offs, blk_sums, nN, nBlk);
  gemm_kernel<D_H><<<dim3((nN + 63) / 64, D_H / 64), 256, 0, stream>>>(x, Wt0, b0, hbuf, nN);
  compact_kernel<<<(nN + 255) / 256, 256, 0, stream>>>(
      sim, col_s, row_ptr, rowsum0, rptr_a, row_a, col_a, w_a, nN);
  spmm_kernel<D_H, true, true><<<(nN * 64 + 255) / 256, 256, 0, stream>>>(
      hbuf, w_a, col_a, rptr_a, wself0, x1, nrm1, nN);

  // ---- layer 1 (active list of layer 0 IS the mask) ----
  att_kernel<<<(nE + 63) / 64, 256, 0, stream>>>(x1, nrm1, row_a, col_a, sim, nE, rptr_a + nN);
  rowdeg_kernel<<<(nN + 255) / 256, 256, 0, stream>>>(sim, rptr_a, rowsum1, wself1, cnt_b, nN);
  block_scan_kernel<<<nBlk, 256, 0, stream>>>(cnt_b, rptr_b, blk_sums, nN);
  scan_sums_kernel<<<1, 256, 0, stream>>>(blk_sums, blk_offs, nBlk);
  add_offs_kernel<<<nBlk, 256, 0, stream>>>(rptr_b, nullptr, blk_offs, blk_sums, nN, nBlk);
  gemm_kernel<D_O><<<dim3((nN + 63) / 64, 1), 256, 0, stream>>>(x1, Wt1, b1, hbuf, nN);
  compact_kernel<<<(nN + 255) / 256, 256, 0, stream>>>(
      sim, col_a, rptr_a, rowsum1, rptr_b, nullptr, col_b, w_b, nN);
  spmm_kernel<D_O, false, false><<<(nN * 64 + 255) / 256, 256, 0, stream>>>(
      hbuf, w_b, col_b, rptr_b, wself1, out, nullptr, nN);
}

// Round 13
// 355.789 us; speedup vs baseline: 1.3704x; 1.0999x over previous
//
#include <hip/hip_runtime.h>
#include <math.h>

// GCNGuard forward: 2 layers of {cosine-sim edge attention -> linear -> SPMM}.
// R3: multi-block scan (113us -> ~4us).
// R4/R6: att 4 edges/subgroup, fully scalarized (LDS-promotion trap fixed).
// R7: active-edge compaction (only ~13% of edges pass sim>=0.1).
// R9: de-atomized scatter. Old scatter: atomicAdd-with-return on critical path
//     (VALUBusy 0.4%) + 2x random 4B stores (WRITE 81.7MB for 6.4MB logical).
//     Now: hist emits rank[e] (atomic already paid there), row_s filled
//     coalesced from CSR, col scatter = computed position, no atomics.

constexpr int D_IN = 128;
constexpr int D_H  = 128;
constexpr int D_O  = 64;

typedef unsigned int uint;

// ---------------- node norms: one wave per node (D=128, 2 floats/lane) -------
__global__ __launch_bounds__(256) void node_norm_kernel(
    const float* __restrict__ x, float* __restrict__ nrm, int n) {
  int gid = blockIdx.x * blockDim.x + threadIdx.x;
  int i = gid >> 6;
  if (i >= n) return;
  int l = threadIdx.x & 63;
  float2 v = *reinterpret_cast<const float2*>(x + (size_t)i * 128 + l * 2);
  float s = v.x * v.x + v.y * v.y;
#pragma unroll
  for (int m = 1; m < 64; m <<= 1) s += __shfl_xor(s, m);
  if (l == 0) nrm[i] = sqrtf(s);
}

// ---------------- CSR build --------------------------------------------------
// hist + rank capture: the atomic's return value IS the within-row rank.
__global__ __launch_bounds__(256) void hist_kernel(
    const int* __restrict__ row, uint* __restrict__ counts,
    uint* __restrict__ rank, int nE) {
  int e = blockIdx.x * blockDim.x + threadIdx.x;
  if (e < nE) rank[e] = atomicAdd(&counts[row[e]], 1u);
}

// phase 1: per-block exclusive scan of 256 counts, emit block sum
__global__ __launch_bounds__(256) void block_scan_kernel(
    const uint* __restrict__ counts, uint* __restrict__ row_excl,
    uint* __restrict__ blk_sums, int n) {
  __shared__ uint sh[256];
  int t = threadIdx.x;
  int i = blockIdx.x * 256 + t;
  uint v = (i < n) ? counts[i] : 0u;
  sh[t] = v;
  __syncthreads();
#pragma unroll
  for (int off = 1; off < 256; off <<= 1) {
    uint u = (t >= off) ? sh[t - off] : 0u;
    __syncthreads();
    sh[t] += u;
    __syncthreads();
  }
  if (i < n) row_excl[i] = sh[t] - v;         // exclusive-in-block
  if (t == 255) blk_sums[blockIdx.x] = sh[255];
}

// phase 2: scan the block sums (nb <= 256) in one small block
__global__ __launch_bounds__(256) void scan_sums_kernel(
    const uint* __restrict__ blk_sums, uint* __restrict__ blk_offs, int nb) {
  __shared__ uint sh[256];
  int t = threadIdx.x;
  uint v = (t < nb) ? blk_sums[t] : 0u;
  sh[t] = v;
  __syncthreads();
#pragma unroll
  for (int off = 1; off < 256; off <<= 1) {
    uint u = (t >= off) ? sh[t - off] : 0u;
    __syncthreads();
    sh[t] += u;
    __syncthreads();
  }
  if (t < nb) blk_offs[t] = sh[t] - v;        // exclusive block offset
}

// phase 3: add block offsets; rp[n] = grand total
__global__ __launch_bounds__(256) void add_offs_kernel(
    uint* __restrict__ rp, const uint* __restrict__ blk_offs,
    const uint* __restrict__ blk_sums, int n, int nb) {
  int i = blockIdx.x * 256 + threadIdx.x;
  if (i < n) rp[i] += blk_offs[blockIdx.x];
  if (i == n) rp[n] = blk_offs[nb - 1] + blk_sums[nb - 1];
}

// row_s filled coalesced from CSR segments (replaces random row stores)
__global__ __launch_bounds__(256) void fill_row_kernel(
    const uint* __restrict__ rp, uint* __restrict__ row_s, int n) {
  int i = blockIdx.x * blockDim.x + threadIdx.x;
  if (i >= n) return;
  uint p1 = rp[i + 1];
  for (uint p = rp[i]; p < p1; ++p) row_s[p] = (uint)i;
}

// col scatter with precomputed position: NO atomics, 1 random 4B store/edge
__global__ __launch_bounds__(256) void scatter_col_kernel(
    const int* __restrict__ row, const int* __restrict__ col,
    const uint* __restrict__ rank, const uint* __restrict__ row_ptr,
    uint* __restrict__ col_s, int nE) {
  int e = blockIdx.x * blockDim.x + threadIdx.x;
  if (e >= nE) return;
  uint p = row_ptr[row[e]] + rank[e];
  col_s[p] = (uint)col[e];
}

// ---------------- W transpose (once per call, tiny) --------------------------
__global__ __launch_bounds__(256) void transpose_kernel(
    const float* __restrict__ W, float* __restrict__ Wt, int J, int K) {
  int idx = blockIdx.x * blockDim.x + threadIdx.x;
  if (idx >= J * K) return;
  int j = idx >> 7;        // K == 128 always here
  int k = idx & 127;
  Wt[k * J + j] = W[idx];
}

// ---------------- attention SDDMM: 4 edges per 16-lane subgroup --------------
// Fully scalarized (R6). nE_dyn (if non-null) overrides nE_static for
// compacted-list invocation (value = rptr_a[nN], only known on device).
__global__ __launch_bounds__(256) void att_kernel(
    const float* __restrict__ x, const float* __restrict__ nrm,
    const uint* __restrict__ rows, const uint* __restrict__ cols,
    float* __restrict__ sim_out, int nE_static,
    const uint* __restrict__ nE_dyn) {
  int nE = nE_dyn ? (int)*nE_dyn : nE_static;
  int sg = threadIdx.x >> 4;
  int sl = threadIdx.x & 15;
  int p0 = (blockIdx.x * 16 + sg) * 4;
  if (p0 >= nE) return;

  uint r0, r1, r2, r3, c0, c1, c2, c3;
  if (p0 + 3 < nE) {                       // vector idx load (16B-aligned)
    uint4 rr = *reinterpret_cast<const uint4*>(rows + p0);
    uint4 cc = *reinterpret_cast<const uint4*>(cols + p0);
    r0 = rr.x; r1 = rr.y; r2 = rr.z; r3 = rr.w;
    c0 = cc.x; c1 = cc.y; c2 = cc.z; c3 = cc.w;
  } else {
    int q1 = (p0 + 1 < nE) ? p0 + 1 : p0;
    int q2 = (p0 + 2 < nE) ? p0 + 2 : p0;
    int q3 = (p0 + 3 < nE) ? p0 + 3 : p0;
    r0 = rows[p0]; r1 = rows[q1]; r2 = rows[q2]; r3 = rows[q3];
    c0 = cols[p0]; c1 = cols[q1]; c2 = cols[q2]; c3 = cols[q3];
  }

  const float4* xr0 = reinterpret_cast<const float4*>(x + (size_t)r0 * 128);
  const float4* xr1 = reinterpret_cast<const float4*>(x + (size_t)r1 * 128);
  const float4* xr2 = reinterpret_cast<const float4*>(x + (size_t)r2 * 128);
  const float4* xr3 = reinterpret_cast<const float4*>(x + (size_t)r3 * 128);
  const float4* xc0 = reinterpret_cast<const float4*>(x + (size_t)c0 * 128);
  const float4* xc1 = reinterpret_cast<const float4*>(x + (size_t)c1 * 128);
  const float4* xc2 = reinterpret_cast<const float4*>(x + (size_t)c2 * 128);
  const float4* xc3 = reinterpret_cast<const float4*>(x + (size_t)c3 * 128);
  int o0 = sl * 2, o1 = sl * 2 + 1;

  float4 a00 = xr0[o0], a01 = xr0[o1];     // 16 independent dwordx4 loads
  float4 a10 = xr1[o0], a11 = xr1[o1];
  float4 a20 = xr2[o0], a21 = xr2[o1];
  float4 a30 = xr3[o0], a31 = xr3[o1];
  float4 b00 = xc0[o0], b01 = xc0[o1];
  float4 b10 = xc1[o0], b11 = xc1[o1];
  float4 b20 = xc2[o0], b21 = xc2[o1];
  float4 b30 = xc3[o0], b31 = xc3[o1];

  float d0 = a00.x * b00.x + a00.y * b00.y + a00.z * b00.z + a00.w * b00.w +
             a01.x * b01.x + a01.y * b01.y + a01.z * b01.z + a01.w * b01.w;
  float d1 = a10.x * b10.x + a10.y * b10.y + a10.z * b10.z + a10.w * b10.w +
             a11.x * b11.x + a11.y * b11.y + a11.z * b11.z + a11.w * b11.w;
  float d2 = a20.x * b20.x + a20.y * b20.y + a20.z * b20.z + a20.w * b20.w +
             a21.x * b21.x + a21.y * b21.y + a21.z * b21.z + a21.w * b21.w;
  float d3 = a30.x * b30.x + a30.y * b30.y + a30.z * b30.z + a30.w * b30.w +
             a31.x * b31.x + a31.y * b31.y + a31.z * b31.z + a31.w * b31.w;

#pragma unroll
  for (int m = 1; m <= 8; m <<= 1) {
    d0 += __shfl_xor(d0, m);
    d1 += __shfl_xor(d1, m);
    d2 += __shfl_xor(d2, m);
    d3 += __shfl_xor(d3, m);
  }

  // epilogue on lanes 0..3, one edge each (?:-chains -> cndmask, no scratch)
  float dv = (sl == 1) ? d1 : (sl == 2) ? d2 : (sl == 3) ? d3 : d0;
  uint  rv = (sl == 1) ? r1 : (sl == 2) ? r2 : (sl == 3) ? r3 : r0;
  uint  cv = (sl == 1) ? c1 : (sl == 2) ? c2 : (sl == 3) ? c3 : c0;
  if (sl < 4 && p0 + sl < nE) {
    float sim = dv / fmaxf(nrm[rv] * nrm[cv], 1e-12f);
    sim_out[p0 + sl] = (sim >= 0.1f) ? sim : 0.0f;
  }
}

// ---------------- per-row sums + active count + self-loop weight ------------
__global__ __launch_bounds__(256) void rowdeg_kernel(
    const float* __restrict__ sim_s, const uint* __restrict__ rp,
    float* __restrict__ rowsum, float* __restrict__ wself,
    uint* __restrict__ cnt, int n) {
  int i = blockIdx.x * blockDim.x + threadIdx.x;
  if (i >= n) return;
  uint p0 = rp[i], p1 = rp[i + 1];
  float s = 0.f;
  uint d = 0;
  for (uint p = p0; p < p1; ++p) {
    float v = sim_s[p];
    s += v;
    if (v > 0.f) ++d;
  }
  rowsum[i] = s;
  wself[i] = expf(1.0f / ((float)d + 1.0f));
  cnt[i] = d;
}

// ---------------- compact: dense active lists, row-owned segments -----------
__global__ __launch_bounds__(256) void compact_kernel(
    const float* __restrict__ sim_s, const uint* __restrict__ col_in,
    const uint* __restrict__ rp_in, const float* __restrict__ rowsum,
    const uint* __restrict__ rp_out, uint* __restrict__ row_out,
    uint* __restrict__ col_out, float* __restrict__ w_out, int n) {
  int i = blockIdx.x * blockDim.x + threadIdx.x;
  if (i >= n) return;
  uint q = rp_out[i];
  uint p1 = rp_in[i + 1];
  float inv = 1.0f / fmaxf(rowsum[i], 1e-30f);
  for (uint p = rp_in[i]; p < p1; ++p) {
    float s = sim_s[p];
    if (s > 0.0f) {
      col_out[q] = col_in[p];
      w_out[q] = expf(s * inv);
      if (row_out) row_out[q] = (uint)i;
      ++q;
    }
  }
}

// ---------------- f32 GEMM: H[M][DOUT] = X[M][128] @ Wt[128][DOUT] + b ------
template <int DOUT>
__global__ __launch_bounds__(256) void gemm_kernel(
    const float* __restrict__ X, const float* __restrict__ Wt,
    const float* __restrict__ bias, float* __restrict__ H, int M) {
  __shared__ float xs[64][132];   // +4 pad: a-reads land 2-way (free)
  __shared__ float wl[128][64];   // [k][j], staged linearly -> conflict-free
  int i0 = blockIdx.x * 64;
  int j0 = blockIdx.y * 64;
  int t = threadIdx.x;
#pragma unroll
  for (int it = 0; it < 8; ++it) {           // stage W block: 2048 float4
    int idx = it * 256 + t;
    int k = idx >> 4, jq = idx & 15;
    float4 v = *reinterpret_cast<const float4*>(Wt + (size_t)k * DOUT + j0 + jq * 4);
    *reinterpret_cast<float4*>(&wl[k][jq * 4]) = v;
  }
#pragma unroll
  for (int it = 0; it < 8; ++it) {           // stage X tile: 64 rows x 128
    int i = it * 8 + (t >> 5);
    int kq = t & 31;
    int row = i0 + i;
    float4 v = make_float4(0.f, 0.f, 0.f, 0.f);
    if (row < M) v = *reinterpret_cast<const float4*>(X + (size_t)row * 128 + kq * 4);
    *reinterpret_cast<float4*>(&xs[i][kq * 4]) = v;
  }
  __syncthreads();
  int cg = t & 15, rg = t >> 4;
  int r0 = rg * 4, c0 = cg * 4;
  float acc[4][4] = {};
#pragma unroll 8
  for (int k = 0; k < 128; ++k) {
    float4 b4 = *reinterpret_cast<const float4*>(&wl[k][c0]);
    float a0 = xs[r0 + 0][k], a1 = xs[r0 + 1][k];
    float a2 = xs[r0 + 2][k], a3 = xs[r0 + 3][k];
    acc[0][0] += a0 * b4.x; acc[0][1] += a0 * b4.y; acc[0][2] += a0 * b4.z; acc[0][3] += a0 * b4.w;
    acc[1][0] += a1 * b4.x; acc[1][1] += a1 * b4.y; acc[1][2] += a1 * b4.z; acc[1][3] += a1 * b4.w;
    acc[2][0] += a2 * b4.x; acc[2][1] += a2 * b4.y; acc[2][2] += a2 * b4.z; acc[2][3] += a2 * b4.w;
    acc[3][0] += a3 * b4.x; acc[3][1] += a3 * b4.y; acc[3][2] += a3 * b4.z; acc[3][3] += a3 * b4.w;
  }
  float4 bb = *reinterpret_cast<const float4*>(bias + j0 + c0);
#pragma unroll
  for (int r = 0; r < 4; ++r) {
    int row = i0 + r0 + r;
    if (row < M) {
      float4 o = make_float4(acc[r][0] + bb.x, acc[r][1] + bb.y,
                             acc[r][2] + bb.z, acc[r][3] + bb.w);
      *reinterpret_cast<float4*>(H + (size_t)row * DOUT + j0 + c0) = o;
    }
  }
}

// ---------------- SPMM over compacted lists: wave/row, branch-free ----------
template <int D, bool RELU, bool WRITE_NORM>
__global__ __launch_bounds__(256) void spmm_kernel(
    const float* __restrict__ H, const float* __restrict__ w_e,
    const uint* __restrict__ col_e, const uint* __restrict__ rp,
    const float* __restrict__ wself, float* __restrict__ out,
    float* __restrict__ norm_out, int n) {
  int gid = blockIdx.x * blockDim.x + threadIdx.x;
  int i = gid >> 6;
  if (i >= n) return;
  int l = threadIdx.x & 63;
  float ws = wself[i];
  uint p1 = rp[i + 1];

  if constexpr (D == 128) {
    float2 hv = *reinterpret_cast<const float2*>(H + (size_t)i * 128 + l * 2);
    float ax = ws * hv.x, ay = ws * hv.y;
    for (uint p = rp[i]; p < p1; ++p) {
      float w = w_e[p];
      uint c = col_e[p];
      float2 hc = *reinterpret_cast<const float2*>(H + (size_t)c * 128 + l * 2);
      ax += w * hc.x;
      ay += w * hc.y;
    }
    if (RELU) { ax = fmaxf(ax, 0.f); ay = fmaxf(ay, 0.f); }
    float2 o; o.x = ax; o.y = ay;
    *reinterpret_cast<float2*>(out + (size_t)i * 128 + l * 2) = o;
    if (WRITE_NORM) {
      float s = ax * ax + ay * ay;
#pragma unroll
      for (int m = 1; m < 64; m <<= 1) s += __shfl_xor(s, m);
      if (l == 0) norm_out[i] = sqrtf(s);
    }
  } else {  // D == 64
    float a = ws * H[(size_t)i * 64 + l];
    for (uint p = rp[i]; p < p1; ++p) {
      float w = w_e[p];
      uint c = col_e[p];
      a += w * H[(size_t)c * 64 + l];
    }
    if (RELU) a = fmaxf(a, 0.f);
    out[(size_t)i * 64 + l] = a;
    if (WRITE_NORM) {
      float s = a * a;
#pragma unroll
      for (int m = 1; m < 64; m <<= 1) s += __shfl_xor(s, m);
      if (l == 0) norm_out[i] = sqrtf(s);
    }
  }
}

// ---------------- launch -----------------------------------------------------
extern "C" void kernel_launch(void* const* d_in, const int* in_sizes, int n_in,
                              void* d_out, int out_size, void* d_ws, size_t ws_size,
                              hipStream_t stream) {
  const float* x  = (const float*)d_in[0];
  const float* W0 = (const float*)d_in[1];
  const float* b0 = (const float*)d_in[2];
  const float* W1 = (const float*)d_in[3];
  const float* b1 = (const float*)d_in[4];
  const int* erow = (const int*)d_in[5];
  const int* ecol = (const int*)d_in[6];
  float* out = (float*)d_out;

  int nN = in_sizes[0] / D_IN;  // 50000
  int nE = in_sizes[5];         // 800000
  int nBlk = (nN + 255) / 256;  // 196 scan blocks

  char* w = (char*)d_ws;
  auto alloc = [&](size_t bytes) {
    char* p = w;
    w += (bytes + 255) & ~(size_t)255;
    return p;
  };
  uint* counts   = (uint*)alloc((size_t)nN * 4);
  uint* row_ptr  = (uint*)alloc(((size_t)nN + 1) * 4);
  uint* blk_sums = (uint*)alloc((size_t)nBlk * 4);
  uint* blk_offs = (uint*)alloc((size_t)nBlk * 4);
  uint* row_s    = (uint*)alloc((size_t)nE * 4);
  uint* col_s    = (uint*)alloc((size_t)nE * 4);
  float* sim     = (float*)alloc((size_t)nE * 4);   // sim0, then simA (layer1)
  float* nrm0    = (float*)alloc((size_t)nN * 4);
  float* nrm1    = (float*)alloc((size_t)nN * 4);
  float* rowsum0 = (float*)alloc((size_t)nN * 4);
  float* rowsum1 = (float*)alloc((size_t)nN * 4);
  float* wself0  = (float*)alloc((size_t)nN * 4);
  float* wself1  = (float*)alloc((size_t)nN * 4);
  uint* cnt_a    = (uint*)alloc((size_t)nN * 4);
  uint* rptr_a   = (uint*)alloc(((size_t)nN + 1) * 4);
  uint* cnt_b    = (uint*)alloc((size_t)nN * 4);
  uint* rptr_b   = (uint*)alloc(((size_t)nN + 1) * 4);
  uint* row_a    = (uint*)alloc((size_t)nE * 4);   // also aliased as rank[]
  uint* col_a    = (uint*)alloc((size_t)nE * 4);
  float* w_a     = (float*)alloc((size_t)nE * 4);
  float* Wt0     = (float*)alloc((size_t)D_IN * D_H * 4);
  float* Wt1     = (float*)alloc((size_t)D_H * D_O * 4);
  float* hbuf    = (float*)alloc((size_t)nN * D_H * 4);
  float* x1      = (float*)alloc((size_t)nN * D_H * 4);
  // aliases: rank (hist->scatter_col) uses row_a, dead until compact0.
  // layer-1 compacted lists alias row_s/col_s (dead after att0/compact0).
  uint* rank     = row_a;
  uint* col_b    = row_s;
  float* w_b     = (float*)col_s;

  hipMemsetAsync(counts, 0, (size_t)nN * 4, stream);

  node_norm_kernel<<<(nN * 64 + 255) / 256, 256, 0, stream>>>(x, nrm0, nN);
  hist_kernel<<<(nE + 255) / 256, 256, 0, stream>>>(erow, counts, rank, nE);
  block_scan_kernel<<<nBlk, 256, 0, stream>>>(counts, row_ptr, blk_sums, nN);
  scan_sums_kernel<<<1, 256, 0, stream>>>(blk_sums, blk_offs, nBlk);
  add_offs_kernel<<<nBlk, 256, 0, stream>>>(row_ptr, blk_offs, blk_sums, nN, nBlk);
  fill_row_kernel<<<(nN + 255) / 256, 256, 0, stream>>>(row_ptr, row_s, nN);
  scatter_col_kernel<<<(nE + 255) / 256, 256, 0, stream>>>(
      erow, ecol, rank, row_ptr, col_s, nE);
  transpose_kernel<<<(D_H * D_IN + 255) / 256, 256, 0, stream>>>(W0, Wt0, D_H, D_IN);
  transpose_kernel<<<(D_O * D_H + 255) / 256, 256, 0, stream>>>(W1, Wt1, D_O, D_H);

  // ---- layer 0 ----
  att_kernel<<<(nE + 63) / 64, 256, 0, stream>>>(x, nrm0, row_s, col_s, sim, nE, nullptr);
  rowdeg_kernel<<<(nN + 255) / 256, 256, 0, stream>>>(sim, row_ptr, rowsum0, wself0, cnt_a, nN);
  block_scan_kernel<<<nBlk, 256, 0, stream>>>(cnt_a, rptr_a, blk_sums, nN);
  scan_sums_kernel<<<1, 256, 0, stream>>>(blk_sums, blk_offs, nBlk);
  add_offs_kernel<<<nBlk, 256, 0, stream>>>(rptr_a, blk_offs, blk_sums, nN, nBlk);
  gemm_kernel<D_H><<<dim3((nN + 63) / 64, D_H / 64), 256, 0, stream>>>(x, Wt0, b0, hbuf, nN);
  compact_kernel<<<(nN + 255) / 256, 256, 0, stream>>>(
      sim, col_s, row_ptr, rowsum0, rptr_a, row_a, col_a, w_a, nN);
  spmm_kernel<D_H, true, true><<<(nN * 64 + 255) / 256, 256, 0, stream>>>(
      hbuf, w_a, col_a, rptr_a, wself0, x1, nrm1, nN);

  // ---- layer 1 (active list of layer 0 IS the mask) ----
  att_kernel<<<(nE + 63) / 64, 256, 0, stream>>>(x1, nrm1, row_a, col_a, sim, nE, rptr_a + nN);
  rowdeg_kernel<<<(nN + 255) / 256, 256, 0, stream>>>(sim, rptr_a, rowsum1, wself1, cnt_b, nN);
  block_scan_kernel<<<nBlk, 256, 0, stream>>>(cnt_b, rptr_b, blk_sums, nN);
  scan_sums_kernel<<<1, 256, 0, stream>>>(blk_sums, blk_offs, nBlk);
  add_offs_kernel<<<nBlk, 256, 0, stream>>>(rptr_b, blk_offs, blk_sums, nN, nBlk);
  gemm_kernel<D_O><<<dim3((nN + 63) / 64, 1), 256, 0, stream>>>(x1, Wt1, b1, hbuf, nN);
  compact_kernel<<<(nN + 255) / 256, 256, 0, stream>>>(
      sim, col_a, rptr_a, rowsum1, rptr_b, nullptr, col_b, w_b, nN);
  spmm_kernel<D_O, false, false><<<(nN * 64 + 255) / 256, 256, 0, stream>>>(
      hbuf, w_b, col_b, rptr_b, wself1, out, nullptr, nN);
}

// Round 15
// 352.584 us; speedup vs baseline: 1.3828x; 1.0091x over previous
//
#include <hip/hip_runtime.h>
#include <math.h>

// GCNGuard forward: 2 layers of {cosine-sim edge attention -> linear -> SPMM}.
// R3: multi-block scan (113us -> ~4us).
// R4/R6: att 4 edges/subgroup, fully scalarized (LDS-promotion trap fixed).
// R7: active-edge compaction (only ~13% of edges pass sim>=0.1).
// R9: de-atomized scatter (hist emits rank; col scatter = computed position).
// R13: att VGPR=36 proved the scheduler SANK the 16 payload loads to their
//      uses (serializing the gather pipeline). sched_barrier(0) after the
//      load block pins all 32 dwordx4 loads before the first FMA.

constexpr int D_IN = 128;
constexpr int D_H  = 128;
constexpr int D_O  = 64;

typedef unsigned int uint;

// ---------------- node norms: one wave per node (D=128, 2 floats/lane) -------
__global__ __launch_bounds__(256) void node_norm_kernel(
    const float* __restrict__ x, float* __restrict__ nrm, int n) {
  int gid = blockIdx.x * blockDim.x + threadIdx.x;
  int i = gid >> 6;
  if (i >= n) return;
  int l = threadIdx.x & 63;
  float2 v = *reinterpret_cast<const float2*>(x + (size_t)i * 128 + l * 2);
  float s = v.x * v.x + v.y * v.y;
#pragma unroll
  for (int m = 1; m < 64; m <<= 1) s += __shfl_xor(s, m);
  if (l == 0) nrm[i] = sqrtf(s);
}

// ---------------- CSR build --------------------------------------------------
// hist + rank capture: the atomic's return value IS the within-row rank.
__global__ __launch_bounds__(256) void hist_kernel(
    const int* __restrict__ row, uint* __restrict__ counts,
    uint* __restrict__ rank, int nE) {
  int e = blockIdx.x * blockDim.x + threadIdx.x;
  if (e < nE) rank[e] = atomicAdd(&counts[row[e]], 1u);
}

// phase 1: per-block exclusive scan of 256 counts, emit block sum
__global__ __launch_bounds__(256) void block_scan_kernel(
    const uint* __restrict__ counts, uint* __restrict__ row_excl,
    uint* __restrict__ blk_sums, int n) {
  __shared__ uint sh[256];
  int t = threadIdx.x;
  int i = blockIdx.x * 256 + t;
  uint v = (i < n) ? counts[i] : 0u;
  sh[t] = v;
  __syncthreads();
#pragma unroll
  for (int off = 1; off < 256; off <<= 1) {
    uint u = (t >= off) ? sh[t - off] : 0u;
    __syncthreads();
    sh[t] += u;
    __syncthreads();
  }
  if (i < n) row_excl[i] = sh[t] - v;         // exclusive-in-block
  if (t == 255) blk_sums[blockIdx.x] = sh[255];
}

// phase 2: scan the block sums (nb <= 256) in one small block
__global__ __launch_bounds__(256) void scan_sums_kernel(
    const uint* __restrict__ blk_sums, uint* __restrict__ blk_offs, int nb) {
  __shared__ uint sh[256];
  int t = threadIdx.x;
  uint v = (t < nb) ? blk_sums[t] : 0u;
  sh[t] = v;
  __syncthreads();
#pragma unroll
  for (int off = 1; off < 256; off <<= 1) {
    uint u = (t >= off) ? sh[t - off] : 0u;
    __syncthreads();
    sh[t] += u;
    __syncthreads();
  }
  if (t < nb) blk_offs[t] = sh[t] - v;        // exclusive block offset
}

// phase 3: add block offsets; rp[n] = grand total
__global__ __launch_bounds__(256) void add_offs_kernel(
    uint* __restrict__ rp, const uint* __restrict__ blk_offs,
    const uint* __restrict__ blk_sums, int n, int nb) {
  int i = blockIdx.x * 256 + threadIdx.x;
  if (i < n) rp[i] += blk_offs[blockIdx.x];
  if (i == n) rp[n] = blk_offs[nb - 1] + blk_sums[nb - 1];
}

// row_s filled coalesced from CSR segments (replaces random row stores)
__global__ __launch_bounds__(256) void fill_row_kernel(
    const uint* __restrict__ rp, uint* __restrict__ row_s, int n) {
  int i = blockIdx.x * blockDim.x + threadIdx.x;
  if (i >= n) return;
  uint p1 = rp[i + 1];
  for (uint p = rp[i]; p < p1; ++p) row_s[p] = (uint)i;
}

// col scatter with precomputed position: NO atomics, 1 random 4B store/edge
__global__ __launch_bounds__(256) void scatter_col_kernel(
    const int* __restrict__ row, const int* __restrict__ col,
    const uint* __restrict__ rank, const uint* __restrict__ row_ptr,
    uint* __restrict__ col_s, int nE) {
  int e = blockIdx.x * blockDim.x + threadIdx.x;
  if (e >= nE) return;
  uint p = row_ptr[row[e]] + rank[e];
  col_s[p] = (uint)col[e];
}

// ---------------- W transpose (once per call, tiny) --------------------------
__global__ __launch_bounds__(256) void transpose_kernel(
    const float* __restrict__ W, float* __restrict__ Wt, int J, int K) {
  int idx = blockIdx.x * blockDim.x + threadIdx.x;
  if (idx >= J * K) return;
  int j = idx >> 7;        // K == 128 always here
  int k = idx & 127;
  Wt[k * J + j] = W[idx];
}

// ---------------- attention SDDMM: 4 edges per 16-lane subgroup --------------
// Fully scalarized (R6); sched_barrier pins all 16 payload loads in flight
// (R13). nE_dyn (if non-null) overrides nE_static for compacted invocation.
__global__ __launch_bounds__(256) void att_kernel(
    const float* __restrict__ x, const float* __restrict__ nrm,
    const uint* __restrict__ rows, const uint* __restrict__ cols,
    float* __restrict__ sim_out, int nE_static,
    const uint* __restrict__ nE_dyn) {
  int nE = nE_dyn ? (int)*nE_dyn : nE_static;
  int sg = threadIdx.x >> 4;
  int sl = threadIdx.x & 15;
  int p0 = (blockIdx.x * 16 + sg) * 4;
  if (p0 >= nE) return;

  uint r0, r1, r2, r3, c0, c1, c2, c3;
  if (p0 + 3 < nE) {                       // vector idx load (16B-aligned)
    uint4 rr = *reinterpret_cast<const uint4*>(rows + p0);
    uint4 cc = *reinterpret_cast<const uint4*>(cols + p0);
    r0 = rr.x; r1 = rr.y; r2 = rr.z; r3 = rr.w;
    c0 = cc.x; c1 = cc.y; c2 = cc.z; c3 = cc.w;
  } else {
    int q1 = (p0 + 1 < nE) ? p0 + 1 : p0;
    int q2 = (p0 + 2 < nE) ? p0 + 2 : p0;
    int q3 = (p0 + 3 < nE) ? p0 + 3 : p0;
    r0 = rows[p0]; r1 = rows[q1]; r2 = rows[q2]; r3 = rows[q3];
    c0 = cols[p0]; c1 = cols[q1]; c2 = cols[q2]; c3 = cols[q3];
  }

  const float4* xr0 = reinterpret_cast<const float4*>(x + (size_t)r0 * 128);
  const float4* xr1 = reinterpret_cast<const float4*>(x + (size_t)r1 * 128);
  const float4* xr2 = reinterpret_cast<const float4*>(x + (size_t)r2 * 128);
  const float4* xr3 = reinterpret_cast<const float4*>(x + (size_t)r3 * 128);
  const float4* xc0 = reinterpret_cast<const float4*>(x + (size_t)c0 * 128);
  const float4* xc1 = reinterpret_cast<const float4*>(x + (size_t)c1 * 128);
  const float4* xc2 = reinterpret_cast<const float4*>(x + (size_t)c2 * 128);
  const float4* xc3 = reinterpret_cast<const float4*>(x + (size_t)c3 * 128);
  int o0 = sl * 2, o1 = sl * 2 + 1;

  float4 a00 = xr0[o0], a01 = xr0[o1];     // 16 independent dwordx4 loads
  float4 a10 = xr1[o0], a11 = xr1[o1];
  float4 a20 = xr2[o0], a21 = xr2[o1];
  float4 a30 = xr3[o0], a31 = xr3[o1];
  float4 b00 = xc0[o0], b01 = xc0[o1];
  float4 b10 = xc1[o0], b11 = xc1[o1];
  float4 b20 = xc2[o0], b21 = xc2[o1];
  float4 b30 = xc3[o0], b31 = xc3[o1];

  // R13: forbid the scheduler from sinking the loads into the FMA chain --
  // all 16 gathers must be issued (in flight) before the first use.
  __builtin_amdgcn_sched_barrier(0);

  float d0 = a00.x * b00.x + a00.y * b00.y + a00.z * b00.z + a00.w * b00.w +
             a01.x * b01.x + a01.y * b01.y + a01.z * b01.z + a01.w * b01.w;
  float d1 = a10.x * b10.x + a10.y * b10.y + a10.z * b10.z + a10.w * b10.w +
             a11.x * b11.x + a11.y * b11.y + a11.z * b11.z + a11.w * b11.w;
  float d2 = a20.x * b20.x + a20.y * b20.y + a20.z * b20.z + a20.w * b20.w +
             a21.x * b21.x + a21.y * b21.y + a21.z * b21.z + a21.w * b21.w;
  float d3 = a30.x * b30.x + a30.y * b30.y + a30.z * b30.z + a30.w * b30.w +
             a31.x * b31.x + a31.y * b31.y + a31.z * b31.z + a31.w * b31.w;

#pragma unroll
  for (int m = 1; m <= 8; m <<= 1) {
    d0 += __shfl_xor(d0, m);
    d1 += __shfl_xor(d1, m);
    d2 += __shfl_xor(d2, m);
    d3 += __shfl_xor(d3, m);
  }

  // epilogue on lanes 0..3, one edge each (?:-chains -> cndmask, no scratch)
  float dv = (sl == 1) ? d1 : (sl == 2) ? d2 : (sl == 3) ? d3 : d0;
  uint  rv = (sl == 1) ? r1 : (sl == 2) ? r2 : (sl == 3) ? r3 : r0;
  uint  cv = (sl == 1) ? c1 : (sl == 2) ? c2 : (sl == 3) ? c3 : c0;
  if (sl < 4 && p0 + sl < nE) {
    float sim = dv / fmaxf(nrm[rv] * nrm[cv], 1e-12f);
    sim_out[p0 + sl] = (sim >= 0.1f) ? sim : 0.0f;
  }
}

// ---------------- per-row sums + active count + self-loop weight ------------
__global__ __launch_bounds__(256) void rowdeg_kernel(
    const float* __restrict__ sim_s, const uint* __restrict__ rp,
    float* __restrict__ rowsum, float* __restrict__ wself,
    uint* __restrict__ cnt, int n) {
  int i = blockIdx.x * blockDim.x + threadIdx.x;
  if (i >= n) return;
  uint p0 = rp[i], p1 = rp[i + 1];
  float s = 0.f;
  uint d = 0;
  for (uint p = p0; p < p1; ++p) {
    float v = sim_s[p];
    s += v;
    if (v > 0.f) ++d;
  }
  rowsum[i] = s;
  wself[i] = expf(1.0f / ((float)d + 1.0f));
  cnt[i] = d;
}

// ---------------- compact: dense active lists, row-owned segments -----------
__global__ __launch_bounds__(256) void compact_kernel(
    const float* __restrict__ sim_s, const uint* __restrict__ col_in,
    const uint* __restrict__ rp_in, const float* __restrict__ rowsum,
    const uint* __restrict__ rp_out, uint* __restrict__ row_out,
    uint* __restrict__ col_out, float* __restrict__ w_out, int n) {
  int i = blockIdx.x * blockDim.x + threadIdx.x;
  if (i >= n) return;
  uint q = rp_out[i];
  uint p1 = rp_in[i + 1];
  float inv = 1.0f / fmaxf(rowsum[i], 1e-30f);
  for (uint p = rp_in[i]; p < p1; ++p) {
    float s = sim_s[p];
    if (s > 0.0f) {
      col_out[q] = col_in[p];
      w_out[q] = expf(s * inv);
      if (row_out) row_out[q] = (uint)i;
      ++q;
    }
  }
}

// ---------------- f32 GEMM: H[M][DOUT] = X[M][128] @ Wt[128][DOUT] + b ------
template <int DOUT>
__global__ __launch_bounds__(256) void gemm_kernel(
    const float* __restrict__ X, const float* __restrict__ Wt,
    const float* __restrict__ bias, float* __restrict__ H, int M) {
  __shared__ float xs[64][132];   // +4 pad: a-reads land 2-way (free)
  __shared__ float wl[128][64];   // [k][j], staged linearly -> conflict-free
  int i0 = blockIdx.x * 64;
  int j0 = blockIdx.y * 64;
  int t = threadIdx.x;
#pragma unroll
  for (int it = 0; it < 8; ++it) {           // stage W block: 2048 float4
    int idx = it * 256 + t;
    int k = idx >> 4, jq = idx & 15;
    float4 v = *reinterpret_cast<const float4*>(Wt + (size_t)k * DOUT + j0 + jq * 4);
    *reinterpret_cast<float4*>(&wl[k][jq * 4]) = v;
  }
#pragma unroll
  for (int it = 0; it < 8; ++it) {           // stage X tile: 64 rows x 128
    int i = it * 8 + (t >> 5);
    int kq = t & 31;
    int row = i0 + i;
    float4 v = make_float4(0.f, 0.f, 0.f, 0.f);
    if (row < M) v = *reinterpret_cast<const float4*>(X + (size_t)row * 128 + kq * 4);
    *reinterpret_cast<float4*>(&xs[i][kq * 4]) = v;
  }
  __syncthreads();
  int cg = t & 15, rg = t >> 4;
  int r0 = rg * 4, c0 = cg * 4;
  float acc[4][4] = {};
#pragma unroll 8
  for (int k = 0; k < 128; ++k) {
    float4 b4 = *reinterpret_cast<const float4*>(&wl[k][c0]);
    float a0 = xs[r0 + 0][k], a1 = xs[r0 + 1][k];
    float a2 = xs[r0 + 2][k], a3 = xs[r0 + 3][k];
    acc[0][0] += a0 * b4.x; acc[0][1] += a0 * b4.y; acc[0][2] += a0 * b4.z; acc[0][3] += a0 * b4.w;
    acc[1][0] += a1 * b4.x; acc[1][1] += a1 * b4.y; acc[1][2] += a1 * b4.z; acc[1][3] += a1 * b4.w;
    acc[2][0] += a2 * b4.x; acc[2][1] += a2 * b4.y; acc[2][2] += a2 * b4.z; acc[2][3] += a2 * b4.w;
    acc[3][0] += a3 * b4.x; acc[3][1] += a3 * b4.y; acc[3][2] += a3 * b4.z; acc[3][3] += a3 * b4.w;
  }
  float4 bb = *reinterpret_cast<const float4*>(bias + j0 + c0);
#pragma unroll
  for (int r = 0; r < 4; ++r) {
    int row = i0 + r0 + r;
    if (row < M) {
      float4 o = make_float4(acc[r][0] + bb.x, acc[r][1] + bb.y,
                             acc[r][2] + bb.z, acc[r][3] + bb.w);
      *reinterpret_cast<float4*>(H + (size_t)row * DOUT + j0 + c0) = o;
    }
  }
}

// ---------------- SPMM over compacted lists: wave/row, branch-free ----------
template <int D, bool RELU, bool WRITE_NORM>
__global__ __launch_bounds__(256) void spmm_kernel(
    const float* __restrict__ H, const float* __restrict__ w_e,
    const uint* __restrict__ col_e, const uint* __restrict__ rp,
    const float* __restrict__ wself, float* __restrict__ out,
    float* __restrict__ norm_out, int n) {
  int gid = blockIdx.x * blockDim.x + threadIdx.x;
  int i = gid >> 6;
  if (i >= n) return;
  int l = threadIdx.x & 63;
  float ws = wself[i];
  uint p1 = rp[i + 1];

  if constexpr (D == 128) {
    float2 hv = *reinterpret_cast<const float2*>(H + (size_t)i * 128 + l * 2);
    float ax = ws * hv.x, ay = ws * hv.y;
    for (uint p = rp[i]; p < p1; ++p) {
      float w = w_e[p];
      uint c = col_e[p];
      float2 hc = *reinterpret_cast<const float2*>(H + (size_t)c * 128 + l * 2);
      ax += w * hc.x;
      ay += w * hc.y;
    }
    if (RELU) { ax = fmaxf(ax, 0.f); ay = fmaxf(ay, 0.f); }
    float2 o; o.x = ax; o.y = ay;
    *reinterpret_cast<float2*>(out + (size_t)i * 128 + l * 2) = o;
    if (WRITE_NORM) {
      float s = ax * ax + ay * ay;
#pragma unroll
      for (int m = 1; m < 64; m <<= 1) s += __shfl_xor(s, m);
      if (l == 0) norm_out[i] = sqrtf(s);
    }
  } else {  // D == 64
    float a = ws * H[(size_t)i * 64 + l];
    for (uint p = rp[i]; p < p1; ++p) {
      float w = w_e[p];
      uint c = col_e[p];
      a += w * H[(size_t)c * 64 + l];
    }
    if (RELU) a = fmaxf(a, 0.f);
    out[(size_t)i * 64 + l] = a;
    if (WRITE_NORM) {
      float s = a * a;
#pragma unroll
      for (int m = 1; m < 64; m <<= 1) s += __shfl_xor(s, m);
      if (l == 0) norm_out[i] = sqrtf(s);
    }
  }
}

// ---------------- launch -----------------------------------------------------
extern "C" void kernel_launch(void* const* d_in, const int* in_sizes, int n_in,
                              void* d_out, int out_size, void* d_ws, size_t ws_size,
                              hipStream_t stream) {
  const float* x  = (const float*)d_in[0];
  const float* W0 = (const float*)d_in[1];
  const float* b0 = (const float*)d_in[2];
  const float* W1 = (const float*)d_in[3];
  const float* b1 = (const float*)d_in[4];
  const int* erow = (const int*)d_in[5];
  const int* ecol = (const int*)d_in[6];
  float* out = (float*)d_out;

  int nN = in_sizes[0] / D_IN;  // 50000
  int nE = in_sizes[5];         // 800000
  int nBlk = (nN + 255) / 256;  // 196 scan blocks

  char* w = (char*)d_ws;
  auto alloc = [&](size_t bytes) {
    char* p = w;
    w += (bytes + 255) & ~(size_t)255;
    return p;
  };
  uint* counts   = (uint*)alloc((size_t)nN * 4);
  uint* row_ptr  = (uint*)alloc(((size_t)nN + 1) * 4);
  uint* blk_sums = (uint*)alloc((size_t)nBlk * 4);
  uint* blk_offs = (uint*)alloc((size_t)nBlk * 4);
  uint* row_s    = (uint*)alloc((size_t)nE * 4);
  uint* col_s    = (uint*)alloc((size_t)nE * 4);
  float* sim     = (float*)alloc((size_t)nE * 4);   // sim0, then simA (layer1)
  float* nrm0    = (float*)alloc((size_t)nN * 4);
  float* nrm1    = (float*)alloc((size_t)nN * 4);
  float* rowsum0 = (float*)alloc((size_t)nN * 4);
  float* rowsum1 = (float*)alloc((size_t)nN * 4);
  float* wself0  = (float*)alloc((size_t)nN * 4);
  float* wself1  = (float*)alloc((size_t)nN * 4);
  uint* cnt_a    = (uint*)alloc((size_t)nN * 4);
  uint* rptr_a   = (uint*)alloc(((size_t)nN + 1) * 4);
  uint* cnt_b    = (uint*)alloc((size_t)nN * 4);
  uint* rptr_b   = (uint*)alloc(((size_t)nN + 1) * 4);
  uint* row_a    = (uint*)alloc((size_t)nE * 4);   // also aliased as rank[]
  uint* col_a    = (uint*)alloc((size_t)nE * 4);
  float* w_a     = (float*)alloc((size_t)nE * 4);
  float* Wt0     = (float*)alloc((size_t)D_IN * D_H * 4);
  float* Wt1     = (float*)alloc((size_t)D_H * D_O * 4);
  float* hbuf    = (float*)alloc((size_t)nN * D_H * 4);
  float* x1      = (float*)alloc((size_t)nN * D_H * 4);
  // aliases: rank (hist->scatter_col) uses row_a, dead until compact0.
  // layer-1 compacted lists alias row_s/col_s (dead after att0/compact0).
  uint* rank     = row_a;
  uint* col_b    = row_s;
  float* w_b     = (float*)col_s;

  hipMemsetAsync(counts, 0, (size_t)nN * 4, stream);

  node_norm_kernel<<<(nN * 64 + 255) / 256, 256, 0, stream>>>(x, nrm0, nN);
  hist_kernel<<<(nE + 255) / 256, 256, 0, stream>>>(erow, counts, rank, nE);
  block_scan_kernel<<<nBlk, 256, 0, stream>>>(counts, row_ptr, blk_sums, nN);
  scan_sums_kernel<<<1, 256, 0, stream>>>(blk_sums, blk_offs, nBlk);
  add_offs_kernel<<<nBlk, 256, 0, stream>>>(row_ptr, blk_offs, blk_sums, nN, nBlk);
  fill_row_kernel<<<(nN + 255) / 256, 256, 0, stream>>>(row_ptr, row_s, nN);
  scatter_col_kernel<<<(nE + 255) / 256, 256, 0, stream>>>(
      erow, ecol, rank, row_ptr, col_s, nE);
  transpose_kernel<<<(D_H * D_IN + 255) / 256, 256, 0, stream>>>(W0, Wt0, D_H, D_IN);
  transpose_kernel<<<(D_O * D_H + 255) / 256, 256, 0, stream>>>(W1, Wt1, D_O, D_H);

  // ---- layer 0 ----
  att_kernel<<<(nE + 63) / 64, 256, 0, stream>>>(x, nrm0, row_s, col_s, sim, nE, nullptr);
  rowdeg_kernel<<<(nN + 255) / 256, 256, 0, stream>>>(sim, row_ptr, rowsum0, wself0, cnt_a, nN);
  block_scan_kernel<<<nBlk, 256, 0, stream>>>(cnt_a, rptr_a, blk_sums, nN);
  scan_sums_kernel<<<1, 256, 0, stream>>>(blk_sums, blk_offs, nBlk);
  add_offs_kernel<<<nBlk, 256, 0, stream>>>(rptr_a, blk_offs, blk_sums, nN, nBlk);
  gemm_kernel<D_H><<<dim3((nN + 63) / 64, D_H / 64), 256, 0, stream>>>(x, Wt0, b0, hbuf, nN);
  compact_kernel<<<(nN + 255) / 256, 256, 0, stream>>>(
      sim, col_s, row_ptr, rowsum0, rptr_a, row_a, col_a, w_a, nN);
  spmm_kernel<D_H, true, true><<<(nN * 64 + 255) / 256, 256, 0, stream>>>(
      hbuf, w_a, col_a, rptr_a, wself0, x1, nrm1, nN);

  // ---- layer 1 (active list of layer 0 IS the mask) ----
  att_kernel<<<(nE + 63) / 64, 256, 0, stream>>>(x1, nrm1, row_a, col_a, sim, nE, rptr_a + nN);
  rowdeg_kernel<<<(nN + 255) / 256, 256, 0, stream>>>(sim, rptr_a, rowsum1, wself1, cnt_b, nN);
  block_scan_kernel<<<nBlk, 256, 0, stream>>>(cnt_b, rptr_b, blk_sums, nN);
  scan_sums_kernel<<<1, 256, 0, stream>>>(blk_sums, blk_offs, nBlk);
  add_offs_kernel<<<nBlk, 256, 0, stream>>>(rptr_b, blk_offs, blk_sums, nN, nBlk);
  gemm_kernel<D_O><<<dim3((nN + 63) / 64, 1), 256, 0, stream>>>(x1, Wt1, b1, hbuf, nN);
  compact_kernel<<<(nN + 255) / 256, 256, 0, stream>>>(
      sim, col_a, rptr_a, rowsum1, rptr_b, nullptr, col_b, w_b, nN);
  spmm_kernel<D_O, false, false><<<(nN * 64 + 255) / 256, 256, 0, stream>>>(
      hbuf, w_b, col_b, rptr_b, wself1, out, nullptr, nN);
}